// Round 1
// baseline (4706.569 us; speedup 1.0000x reference)
//
#include <hip/hip_runtime.h>
#include <hip/hip_bf16.h>
#include <stdint.h>

typedef unsigned short u16;
typedef unsigned int u32;
typedef unsigned long long u64;
typedef float f32x4 __attribute__((ext_vector_type(4)));
typedef short bf16x8 __attribute__((ext_vector_type(8)));

#define NB 32
#define NL 1024
#define ND 512
#define NH 512
#define G4 2048
#define NOUT 100
#define NFF 256
#define HSTR 528   // LDS row stride (halfwords): 264 dwords == 8 mod 32 -> 2-way (free) a-frag reads

__device__ inline u16 f2b(float f) {
    union { float f; unsigned i; } c; c.f = f;
    unsigned i = c.i;
    return (u16)((i + 0x7FFFu + ((i >> 16) & 1u)) >> 16);
}
__device__ inline bf16x8 cvt8(const float* __restrict__ p) {
    float4 a = *(const float4*)p;
    float4 b = *(const float4*)(p + 4);
    bf16x8 r;
    u16* h = (u16*)&r;
    h[0] = f2b(a.x); h[1] = f2b(a.y); h[2] = f2b(a.z); h[3] = f2b(a.w);
    h[4] = f2b(b.x); h[5] = f2b(b.y); h[6] = f2b(b.z); h[7] = f2b(b.w);
    return r;
}
__device__ inline f32x4 MF(bf16x8 a, bf16x8 b, f32x4 c) {
    return __builtin_amdgcn_mfma_f32_16x16x32_bf16(a, b, c, 0, 0, 0);
}
__device__ inline float tanh_f(float x) {
    float xx = fminf(fmaxf(x, -15.f), 15.f);
    float e = __expf(2.f * xx);
    return (e - 1.f) / (e + 1.f);
}
__device__ inline float sigm_f(float x) { return 1.f / (1.f + __expf(-x)); }

// cbias[b][r] = emb[concepts[b]] . Wih[r, 512:1024] + bih[r] + bhh[r]   (all fp32)
__global__ __launch_bounds__(256) void k_cbias(const float* __restrict__ emb,
                                               const int* __restrict__ concepts,
                                               const float* __restrict__ Wih,
                                               const float* __restrict__ bih,
                                               const float* __restrict__ bhh,
                                               float* __restrict__ cbias) {
    __shared__ float e[ND];
    int b = blockIdx.x;
    int r = blockIdx.y * 256 + threadIdx.x;
    int c = concepts[b];
    for (int i = threadIdx.x; i < ND; i += 256) e[i] = emb[c * ND + i];
    __syncthreads();
    const float* wrow = Wih + (size_t)r * 1024 + 512;
    float acc = 0.f;
#pragma unroll 4
    for (int k4 = 0; k4 < 128; k4++) {
        float4 wv = *(const float4*)&wrow[k4 * 4];
        acc += e[k4 * 4 + 0] * wv.x + e[k4 * 4 + 1] * wv.y +
               e[k4 * 4 + 2] * wv.z + e[k4 * 4 + 3] * wv.w;
    }
    cbias[b * G4 + r] = acc + bih[r] + bhh[r];
}

// Persistent LSTM, batch-split: 8 groups (one XCD each via blockIdx&7) x 32 blocks.
// Group g owns batch rows [4g,4g+4); block k owns h lanes [16k,16k+16) (64 gate rows).
// v2 structure:
//  - All weight B-fragments live in REGISTERS (bwx[16]/bwh[16], 128 VGPR): 1 wave/SIMD
//    resident (grid=256 blocks) so up to 512 VGPR available; removes 128 KB LDS and all
//    B-fragment ds_read_b128 traffic from the serial MFMA phases.
//  - Single-hop h exchange: h element -> u32 = (t+1)<<16 | bf16(h), relaxed agent store.
//    No vmcnt drain, no flag, no pack shuffles. Consumers poll the tagged data itself
//    (per-element tag check => no ordering assumptions needed; tags can only lag, never
//    lead, so ==t is safe). Poll loads issued BEFORE the x-MFMA to hide L2 latency.
//  - x prefetch depth 2: issue x[t+2] at iter t, commit at iter t+1 (full-step in flight).
__global__ __launch_bounds__(256, 1) void k_lstm(const float* __restrict__ x,
                                                 const float* __restrict__ Wih,
                                                 const float* __restrict__ Whh,
                                                 const float* __restrict__ cbias,
                                                 u16* __restrict__ out,
                                                 u32* __restrict__ hbuf) {
    __shared__ __align__(16) u16 hsb[4 * HSTR];         // h[t-1] tile, bf16
    __shared__ __align__(16) u16 xb[2][4 * HSTR];       // x double buffer, bf16
    __shared__ float gbuf[4 * 68];
    __shared__ float cb_lds[4 * 64];
    int g = blockIdx.x & 7, k = blockIdx.x >> 3;
    int tid = threadIdx.x;
    int w = tid >> 6, l = tid & 63, quad = l >> 4, lane = l & 15;
    int jj = k * 16;
    int b0 = g * 4;
    int rr = tid >> 6, f0 = (tid & 63) * 8;

    // ---- init: weights -> registers (fp32->bf16 fragments), cbias, x[0] -> LDS
    bf16x8 bwx[16], bwh[16];
    {
        int n = l & 15, q4 = l >> 4;
        const float* wsrc = Wih + (size_t)(w * 512 + jj + n) * 1024 + q4 * 8;  // x-part
        const float* hsrc = Whh + (size_t)(w * 512 + jj + n) * 512 + q4 * 8;
#pragma unroll
        for (int kk = 0; kk < 16; kk++) {
            bwx[kk] = cvt8(wsrc + kk * 32);
            bwh[kk] = cvt8(hsrc + kk * 32);
        }
        cb_lds[tid] = cbias[(size_t)(b0 + (tid >> 6)) * G4 +
                            (((tid >> 4) & 3) * 512) + jj + (tid & 15)];
        *(bf16x8*)&xb[0][rr * HSTR + f0] = cvt8(&x[((size_t)(b0 + rr) * NL) * ND + f0]);
    }
    // preload x[1] into prefetch regs (committed at iter 0)
    float4 pa, pb;
    {
        const float* px = &x[((size_t)(b0 + rr) * NL + 1) * ND + f0];
        pa = *(const float4*)px; pb = *(const float4*)(px + 4);
    }
    __syncthreads();

    float c_reg = 0.f;                       // cell state (wave 0 lanes)
    u32* hg = hbuf + (size_t)g * 4096;       // per-group: 2 parity x 2048 u32 (tag|h)

    for (int t = 0; t < NL; t++) {
        // ---- issue first poll attempt for h[t-1] (checked after x-MFMA)
        u32 hv[8];
        const u32* hsrc2 = hg + (((t - 1) & 1) << 11) + tid * 8;
        if (t > 0) {
#pragma unroll
            for (int i = 0; i < 8; i++)
                hv[i] = __hip_atomic_load(&hsrc2[i], __ATOMIC_RELAXED,
                                          __HIP_MEMORY_SCOPE_AGENT);
        }
        // ---- x-part MFMA (wave w = gate block), B-frags from registers
        f32x4 acc = {};
#pragma unroll
        for (int kk = 0; kk < 16; kk++) {
            bf16x8 a = *(bf16x8*)&xb[t & 1][(lane & 3) * HSTR + kk * 32 + quad * 8];
            acc = MF(a, bwx[kk], acc);
        }
        // ---- commit x[t+1] (loads issued one full iteration ago -> no stall)
        if (t + 1 < NL) {
            bf16x8 xv; u16* hh = (u16*)&xv;
            hh[0] = f2b(pa.x); hh[1] = f2b(pa.y); hh[2] = f2b(pa.z); hh[3] = f2b(pa.w);
            hh[4] = f2b(pb.x); hh[5] = f2b(pb.y); hh[6] = f2b(pb.z); hh[7] = f2b(pb.w);
            *(bf16x8*)&xb[(t + 1) & 1][rr * HSTR + f0] = xv;
        }
        // ---- issue x[t+2] prefetch
        if (t + 2 < NL) {
            const float* px = &x[((size_t)(b0 + rr) * NL + (t + 2)) * ND + f0];
            pa = *(const float4*)px; pb = *(const float4*)(px + 4);
        }
        if (t > 0) {
            // ---- poll: every u32 carries its own tag; retry until all fresh
            for (;;) {
                bool ok = true;
#pragma unroll
                for (int i = 0; i < 8; i++) ok &= ((hv[i] >> 16) == (u32)t);
                if (ok) break;
                __builtin_amdgcn_s_sleep(1);
#pragma unroll
                for (int i = 0; i < 8; i++)
                    hv[i] = __hip_atomic_load(&hsrc2[i], __ATOMIC_RELAXED,
                                              __HIP_MEMORY_SCOPE_AGENT);
            }
            {   // stage h[t-1] -> LDS (thread tid: row=tid>>6, cols (tid&63)*8..+7)
                u16 tmp[8];
#pragma unroll
                for (int i = 0; i < 8; i++) tmp[i] = (u16)hv[i];
                *(bf16x8*)&hsb[rr * HSTR + f0] = *(bf16x8*)tmp;
            }
            __syncthreads();   // (C) hsb ready; prev-iter barrier (B) protects vs old reads
#pragma unroll
            for (int kk = 0; kk < 16; kk++) {
                bf16x8 a = *(bf16x8*)&hsb[(lane & 3) * HSTR + kk * 32 + quad * 8];
                acc = MF(a, bwh[kk], acc);
            }
        }
        if (quad == 0) {   // C rows m=0..3 live in quad 0 regs
#pragma unroll
            for (int r = 0; r < 4; r++)
                gbuf[r * 68 + w * 16 + lane] = acc[r];
        }
        __syncthreads();   // (B)
        if (tid < 64) {    // cell (wave 0 only)
            int row = tid >> 4, j = tid & 15;
            float gi = gbuf[row * 68 + 0 * 16 + j] + cb_lds[row * 64 + 0 * 16 + j];
            float gf = gbuf[row * 68 + 1 * 16 + j] + cb_lds[row * 64 + 1 * 16 + j];
            float gg = gbuf[row * 68 + 2 * 16 + j] + cb_lds[row * 64 + 2 * 16 + j];
            float go = gbuf[row * 68 + 3 * 16 + j] + cb_lds[row * 64 + 3 * 16 + j];
            float iv = sigm_f(gi), fv = sigm_f(gf), ov = sigm_f(go);
            float gv = tanh_f(gg);
            c_reg = fv * c_reg + iv * gv;
            u16 hb = f2b(ov * tanh_f(c_reg));
            // single-hop publish: tag+data in one word, fire and forget
            __hip_atomic_store(&hg[((t & 1) << 11) + row * 512 + jj + j],
                               ((u32)(t + 1) << 16) | (u32)hb,
                               __ATOMIC_RELAXED, __HIP_MEMORY_SCOPE_AGENT);
            // lstm_out write off the sync path (pair-packed u32)
            unsigned nb = __shfl_down((unsigned)hb, 1);
            if ((j & 1) == 0)
                *(u32*)&out[((size_t)(b0 + row) * NL + t) * NH + jj + j] =
                    (u32)hb | (nb << 16);
        }
    }
}

// Fused: Q = x@Wm^T+bm (prologue), flash attention with decayed-causal scores,
// FF head relu(W@W1^T+b1)@W2^T+b2 (epilogue). 16-row q tiles, 512 threads.
__global__ __launch_bounds__(512) void k_attn(const float* __restrict__ x,
                                              const float* __restrict__ Wm,
                                              const float* __restrict__ bm,
                                              const u16* __restrict__ kv,
                                              const float* __restrict__ W1,
                                              const float* __restrict__ b1,
                                              const float* __restrict__ W2,
                                              const float* __restrict__ b2,
                                              float* __restrict__ outp) {
    __shared__ __align__(16) u16 Qs[16 * 520];
    __shared__ __align__(16) u16 Vt[512 * 40];
    __shared__ float Sbuf[16 * 33];
    __shared__ __align__(16) u16 Pbuf[16 * 40];
    __shared__ float alpha_s[16];
    __shared__ float l_s[16];
    int b = blockIdx.x, qt = blockIdx.y;
    int tid = threadIdx.x, w = tid >> 6, l = tid & 63, quad = l >> 4, lane = l & 15;

    {   // prologue: Qs[16][512] = x_tile @ Wm^T + bm
        const float* xq = x + ((size_t)b * NL + qt * 16 + lane) * ND;
#pragma unroll
        for (int nt2 = 0; nt2 < 4; nt2++) {
            int n = (w * 4 + nt2) * 16 + lane;
            const float* wmp = Wm + (size_t)n * ND;
            f32x4 aq = {};
#pragma unroll 4
            for (int kk = 0; kk < 16; kk++)
                aq = MF(cvt8(&xq[kk * 32 + quad * 8]), cvt8(&wmp[kk * 32 + quad * 8]), aq);
            float bmv = bm[n];
#pragma unroll
            for (int r = 0; r < 4; r++)
                Qs[(quad * 4 + r) * 520 + n] = f2b(aq[r] + bmv);
        }
    }
    float m_run = -30000.f, l_run = 0.f;
    f32x4 acc[4] = {};
    __syncthreads();

    int st_max = ((qt << 4) + 15) >> 5;
    for (int st = 0; st <= st_max; st++) {
        if (w < 2) {  // QK^T: S[16][32], waves 0..1
            int ni = w;
            f32x4 s = {};
            const u16* krow = kv + ((size_t)b * NL + st * 32 + ni * 16 + lane) * NH;
#pragma unroll 4
            for (int kk = 0; kk < 16; kk++)
                s = MF(*(bf16x8*)&Qs[lane * 520 + kk * 32 + quad * 8],
                       *(const bf16x8*)&krow[kk * 32 + quad * 8], s);
            int scol = st * 32 + ni * 16 + lane;
#pragma unroll
            for (int r = 0; r < 4; r++) {
                int trow = (qt << 4) + quad * 4 + r;
                int dt = trow - scol;
                float v = (dt < 0) ? -30000.f : s[r] * __expf(-0.6f * (float)dt);
                Sbuf[(quad * 4 + r) * 33 + ni * 16 + lane] = v;
            }
        } else if (w >= 4) {  // stage V^T[512][32]
            int t2 = tid & 255;
            int srow = t2 >> 3, dseg = t2 & 7;
            const u16* vsrc = kv + ((size_t)b * NL + st * 32 + srow) * NH + dseg * 64;
#pragma unroll
            for (int i = 0; i < 8; i++) {
                union { uint4 v; u16 h[8]; } u;
                u.v = *(const uint4*)&vsrc[i * 8];
                int d0 = dseg * 64 + i * 8;
#pragma unroll
                for (int j2 = 0; j2 < 8; j2++) Vt[(d0 + j2) * 40 + srow] = u.h[j2];
            }
        }
        __syncthreads();
        if (tid < 16) {  // online softmax
            int m = tid;
            float vmax = -30000.f;
#pragma unroll 8
            for (int n = 0; n < 32; n++) vmax = fmaxf(vmax, Sbuf[m * 33 + n]);
            float mnew = fmaxf(m_run, vmax);
            float al = __expf(m_run - mnew);
            float lsum = 0.f;
#pragma unroll 8
            for (int n = 0; n < 32; n++) {
                float p = __expf(Sbuf[m * 33 + n] - mnew);
                lsum += p;
                Pbuf[m * 40 + n] = f2b(p);
            }
            l_run = l_run * al + lsum;
            m_run = mnew;
            alpha_s[m] = al;
            l_s[m] = l_run;
        }
        __syncthreads();
        {   // PV
            float a0 = alpha_s[quad * 4 + 0];
            float a1 = alpha_s[quad * 4 + 1];
            float a2 = alpha_s[quad * 4 + 2];
            float a3 = alpha_s[quad * 4 + 3];
            bf16x8 afrag = *(bf16x8*)&Pbuf[lane * 40 + quad * 8];
#pragma unroll
            for (int di = 0; di < 4; di++) {
                int dtile = w * 4 + di;
                f32x4 c = acc[di];
                c[0] *= a0; c[1] *= a1; c[2] *= a2; c[3] *= a3;
                acc[di] = MF(afrag, *(bf16x8*)&Vt[(dtile * 16 + lane) * 40 + quad * 8], c);
            }
        }
        __syncthreads();
    }

    u16* Wt = Vt;   // weighted -> LDS
    {
        float li0 = 1.f / l_s[quad * 4 + 0];
        float li1 = 1.f / l_s[quad * 4 + 1];
        float li2 = 1.f / l_s[quad * 4 + 2];
        float li3 = 1.f / l_s[quad * 4 + 3];
#pragma unroll
        for (int di = 0; di < 4; di++) {
            int col = (w * 4 + di) * 16 + lane;
            Wt[(quad * 4 + 0) * 520 + col] = f2b(acc[di][0] * li0);
            Wt[(quad * 4 + 1) * 520 + col] = f2b(acc[di][1] * li1);
            Wt[(quad * 4 + 2) * 520 + col] = f2b(acc[di][2] * li2);
            Wt[(quad * 4 + 3) * 520 + col] = f2b(acc[di][3] * li3);
        }
    }
    __syncthreads();
    u16* H1 = Qs;
    {   // H1[16][256] = relu(Wt @ W1^T + b1)
#pragma unroll
        for (int nt2 = 0; nt2 < 2; nt2++) {
            int n = (w * 2 + nt2) * 16 + lane;
            const float* w1p = W1 + (size_t)n * ND;
            f32x4 a1 = {};
#pragma unroll 4
            for (int kk = 0; kk < 16; kk++)
                a1 = MF(*(bf16x8*)&Wt[lane * 520 + kk * 32 + quad * 8],
                        cvt8(&w1p[kk * 32 + quad * 8]), a1);
            float b1v = b1[n];
#pragma unroll
            for (int r = 0; r < 4; r++)
                H1[(quad * 4 + r) * 264 + n] = f2b(fmaxf(a1[r] + b1v, 0.f));
        }
    }
    __syncthreads();
    if (w < 7) {  // out[16][100] = H1 @ W2^T + b2
        int n = w * 16 + lane;
        int nc = n < NOUT ? n : NOUT - 1;
        const float* w2p = W2 + (size_t)nc * NFF;
        f32x4 a2 = {};
#pragma unroll
        for (int kk = 0; kk < 8; kk++)
            a2 = MF(*(bf16x8*)&H1[lane * 264 + kk * 32 + quad * 8],
                    cvt8(&w2p[kk * 32 + quad * 8]), a2);
        if (n < NOUT) {
            float b2v = b2[n];
#pragma unroll
            for (int r = 0; r < 4; r++)
                outp[((size_t)b * NL + (qt << 4) + quad * 4 + r) * NOUT + n] = a2[r] + b2v;
        }
    }
}

extern "C" void kernel_launch(void* const* d_in, const int* in_sizes, int n_in,
                              void* d_out, int out_size, void* d_ws, size_t ws_size,
                              hipStream_t stream) {
    const float* x        = (const float*)d_in[0];
    const int*   concepts = (const int*)d_in[1];
    const float* emb      = (const float*)d_in[2];
    const float* Wih      = (const float*)d_in[3];
    const float* Whh      = (const float*)d_in[4];
    const float* bih      = (const float*)d_in[5];
    const float* bhh      = (const float*)d_in[6];
    const float* Wm       = (const float*)d_in[7];
    const float* bm       = (const float*)d_in[8];
    const float* W1       = (const float*)d_in[9];
    const float* b1       = (const float*)d_in[10];
    const float* W2       = (const float*)d_in[11];
    const float* b2       = (const float*)d_in[12];
    float* outp = (float*)d_out;

    char* ws = (char*)d_ws;
    size_t off = 0;
    u16* lstm_out = (u16*)(ws + off); off += (size_t)NB * NL * NH * 2;   // 32 MB
    float* cbias  = (float*)(ws + off); off += (size_t)NB * G4 * 4;      // 256 KB
    u32* hbuf     = (u32*)(ws + off); off += (size_t)8 * 4096 * 4;       // 128 KB tagged h

    hipMemsetAsync(hbuf, 0, (size_t)8 * 4096 * 4, stream);  // tags=0 != any expected tag
    k_cbias<<<dim3(NB, G4 / 256), 256, 0, stream>>>(emb, concepts, Wih, bih, bhh, cbias);
    k_lstm<<<256, 256, 0, stream>>>(x, Wih, Whh, cbias, lstm_out, hbuf);
    k_attn<<<dim3(NB, NL / 16), 512, 0, stream>>>(x, Wm, bm, lstm_out, W1, b1, W2, b2, outp);
}

// Round 2
// 3496.105 us; speedup vs baseline: 1.3462x; 1.3462x over previous
//
#include <hip/hip_runtime.h>
#include <hip/hip_bf16.h>
#include <stdint.h>

typedef unsigned short u16;
typedef unsigned int u32;
typedef unsigned long long u64;
typedef float f32x4 __attribute__((ext_vector_type(4)));
typedef short bf16x8 __attribute__((ext_vector_type(8)));

#define NB 32
#define NL 1024
#define ND 512
#define NH 512
#define G4 2048
#define NOUT 100
#define NFF 256
#define HSTR 528   // LDS row stride (halfwords): 264 dwords == 8 mod 32 -> uniform 2-way (free) a-frag reads

__device__ inline u16 f2b(float f) {
    union { float f; unsigned i; } c; c.f = f;
    unsigned i = c.i;
    return (u16)((i + 0x7FFFu + ((i >> 16) & 1u)) >> 16);
}
__device__ inline bf16x8 cvt8(const float* __restrict__ p) {
    float4 a = *(const float4*)p;
    float4 b = *(const float4*)(p + 4);
    bf16x8 r;
    u16* h = (u16*)&r;
    h[0] = f2b(a.x); h[1] = f2b(a.y); h[2] = f2b(a.z); h[3] = f2b(a.w);
    h[4] = f2b(b.x); h[5] = f2b(b.y); h[6] = f2b(b.z); h[7] = f2b(b.w);
    return r;
}
__device__ inline f32x4 MF(bf16x8 a, bf16x8 b, f32x4 c) {
    return __builtin_amdgcn_mfma_f32_16x16x32_bf16(a, b, c, 0, 0, 0);
}
__device__ inline float tanh_f(float x) {
    float xx = fminf(fmaxf(x, -15.f), 15.f);
    float e = __expf(2.f * xx);
    return (e - 1.f) / (e + 1.f);
}
__device__ inline float sigm_f(float x) { return 1.f / (1.f + __expf(-x)); }

// cbias[b][r] = emb[concepts[b]] . Wih[r, 512:1024] + bih[r] + bhh[r]   (all fp32)
__global__ __launch_bounds__(256) void k_cbias(const float* __restrict__ emb,
                                               const int* __restrict__ concepts,
                                               const float* __restrict__ Wih,
                                               const float* __restrict__ bih,
                                               const float* __restrict__ bhh,
                                               float* __restrict__ cbias) {
    __shared__ float e[ND];
    int b = blockIdx.x;
    int r = blockIdx.y * 256 + threadIdx.x;
    int c = concepts[b];
    for (int i = threadIdx.x; i < ND; i += 256) e[i] = emb[c * ND + i];
    __syncthreads();
    const float* wrow = Wih + (size_t)r * 1024 + 512;
    float acc = 0.f;
#pragma unroll 4
    for (int k4 = 0; k4 < 128; k4++) {
        float4 wv = *(const float4*)&wrow[k4 * 4];
        acc += e[k4 * 4 + 0] * wv.x + e[k4 * 4 + 1] * wv.y +
               e[k4 * 4 + 2] * wv.z + e[k4 * 4 + 3] * wv.w;
    }
    cbias[b * G4 + r] = acc + bih[r] + bhh[r];
}

// Persistent LSTM, batch-split: 8 groups (one XCD each via blockIdx&7) x 32 blocks.
// Group g owns batch rows [4g,4g+4); block k owns h lanes [16k,16k+16) (64 gate rows).
// v3 = v0's PROVEN flag+h64 exchange protocol, plus the three counter-validated changes:
//  - Weight B-fragments in REGISTERS (bwx/bwh, 128 VGPR-equivalents; 1 wave/SIMD resident
//    so budget is ample). Removes 128 KB LDS + all weight ds_read_b128 from the hot loop.
//    (v2 A/B: bank conflicts 1.38e8 -> 4.2e6 with this + HSTR change.)
//  - HSTR 520->528: a-fragment ds_read_b128 pattern becomes uniform 2-way (free per m136).
//  - Depth-2 x prefetch with COMMIT AT TOP of iteration: commit x[t+1] from loads issued
//    a full iteration ago, then issue x[t+2]. Keeps the wave-0 `vmcnt(0)` drain before the
//    flag store cheap (outstanding prefetch is ~one iteration old by then).
__global__ __launch_bounds__(256, 1) void k_lstm(const float* __restrict__ x,
                                                 const float* __restrict__ Wih,
                                                 const float* __restrict__ Whh,
                                                 const float* __restrict__ cbias,
                                                 u16* __restrict__ out,
                                                 u64* __restrict__ h64,
                                                 int* __restrict__ flags) {
    __shared__ __align__(16) u16 hsb[4 * HSTR];         // h[t-1] tile, bf16
    __shared__ __align__(16) u16 xb[2][4 * HSTR];       // x double buffer, bf16
    __shared__ float gbuf[4 * 68];
    __shared__ float cb_lds[4 * 64];
    int g = blockIdx.x & 7, k = blockIdx.x >> 3;
    int tid = threadIdx.x;
    int w = tid >> 6, l = tid & 63, quad = l >> 4, lane = l & 15;
    int jj = k * 16;
    int b0 = g * 4;
    int rr = tid >> 6, f0 = (tid & 63) * 8;

    // ---- init: weights -> registers (fp32->bf16 fragments), cbias, x[0] -> LDS
    bf16x8 bwx[16], bwh[16];
    {
        int n = l & 15, q4 = l >> 4;
        const float* wsrc = Wih + (size_t)(w * 512 + jj + n) * 1024 + q4 * 8;  // x-part
        const float* hsrc = Whh + (size_t)(w * 512 + jj + n) * 512 + q4 * 8;
#pragma unroll
        for (int kk = 0; kk < 16; kk++) {
            bwx[kk] = cvt8(wsrc + kk * 32);
            bwh[kk] = cvt8(hsrc + kk * 32);
        }
        cb_lds[tid] = cbias[(size_t)(b0 + (tid >> 6)) * G4 +
                            (((tid >> 4) & 3) * 512) + jj + (tid & 15)];
        *(bf16x8*)&xb[0][rr * HSTR + f0] = cvt8(&x[((size_t)(b0 + rr) * NL) * ND + f0]);
    }
    // preload x[1] into prefetch regs (committed at top of iter 0)
    float4 pa, pb;
    {
        const float* px = &x[((size_t)(b0 + rr) * NL + 1) * ND + f0];
        pa = *(const float4*)px; pb = *(const float4*)(px + 4);
    }
    __syncthreads();

    float c_reg = 0.f;                       // cell state (wave 0 lanes)
    u64* h64g = h64 + (size_t)g * 1024;      // per-group: 2 parity x 512 u64
    int* flg = flags + g * 32 * 16;          // per-block flag, 64 B apart

    for (int t = 0; t < NL; t++) {
        // ---- commit x[t+1] (loads issued one full iteration ago -> no stall)
        if (t + 1 < NL) {
            bf16x8 xv; u16* hh = (u16*)&xv;
            hh[0] = f2b(pa.x); hh[1] = f2b(pa.y); hh[2] = f2b(pa.z); hh[3] = f2b(pa.w);
            hh[4] = f2b(pb.x); hh[5] = f2b(pb.y); hh[6] = f2b(pb.z); hh[7] = f2b(pb.w);
            *(bf16x8*)&xb[(t + 1) & 1][rr * HSTR + f0] = xv;
        }
        // ---- issue x[t+2] prefetch (full iteration of latency hiding ahead)
        if (t + 2 < NL) {
            const float* px = &x[((size_t)(b0 + rr) * NL + (t + 2)) * ND + f0];
            pa = *(const float4*)px; pb = *(const float4*)(px + 4);
        }
        // ---- x-part MFMA (wave w = gate block), B-frags from registers
        f32x4 acc = {};
#pragma unroll
        for (int kk = 0; kk < 16; kk++) {
            bf16x8 a = *(bf16x8*)&xb[t & 1][(lane & 3) * HSTR + kk * 32 + quad * 8];
            acc = MF(a, bwx[kk], acc);
        }
        if (t > 0) {
            if (tid < 32) {   // wave 0: one lane per producer flag
                for (;;) {
                    int v = __hip_atomic_load(&flg[tid * 16], __ATOMIC_RELAXED,
                                              __HIP_MEMORY_SCOPE_AGENT);
                    if (__ballot(v < t) == 0ull) break;
                    __builtin_amdgcn_s_sleep(2);
                }
            }
            __syncthreads();   // (A)
            {   // stage h[t-1]: 512 u64, 2 per thread, coalesced
                const u64* src = h64g + (size_t)((t - 1) & 1) * 512;
                u64 v0 = __hip_atomic_load(&src[tid], __ATOMIC_RELAXED,
                                           __HIP_MEMORY_SCOPE_AGENT);
                u64 v1 = __hip_atomic_load(&src[tid + 256], __ATOMIC_RELAXED,
                                           __HIP_MEMORY_SCOPE_AGENT);
                *(u64*)&hsb[(tid >> 7) * HSTR + (tid & 127) * 4] = v0;
                *(u64*)&hsb[((tid + 256) >> 7) * HSTR + ((tid + 256) & 127) * 4] = v1;
            }
            __syncthreads();   // (C)
#pragma unroll
            for (int kk = 0; kk < 16; kk++) {
                bf16x8 a = *(bf16x8*)&hsb[(lane & 3) * HSTR + kk * 32 + quad * 8];
                acc = MF(a, bwh[kk], acc);
            }
        }
        if (quad == 0) {   // C rows m=0..3 live in quad 0 regs
#pragma unroll
            for (int r = 0; r < 4; r++)
                gbuf[r * 68 + w * 16 + lane] = acc[r];
        }
        __syncthreads();   // (B)
        if (tid < 64) {    // cell (wave 0 only); no trailing block barrier
            int row = tid >> 4, j = tid & 15;
            float gi = gbuf[row * 68 + 0 * 16 + j] + cb_lds[row * 64 + 0 * 16 + j];
            float gf = gbuf[row * 68 + 1 * 16 + j] + cb_lds[row * 64 + 1 * 16 + j];
            float gg = gbuf[row * 68 + 2 * 16 + j] + cb_lds[row * 64 + 2 * 16 + j];
            float go = gbuf[row * 68 + 3 * 16 + j] + cb_lds[row * 64 + 3 * 16 + j];
            float iv = sigm_f(gi), fv = sigm_f(gf), ov = sigm_f(go);
            float gv = tanh_f(gg);
            c_reg = fv * c_reg + iv * gv;
            u16 hb = f2b(ov * tanh_f(c_reg));
            unsigned hb32 = (unsigned)hb;
            unsigned v1 = __shfl_down(hb32, 1);
            unsigned v2 = __shfl_down(hb32, 2);
            unsigned v3 = __shfl_down(hb32, 3);
            u64 pk = (u64)hb32 | ((u64)v1 << 16) | ((u64)v2 << 32) | ((u64)v3 << 48);
            if ((j & 3) == 0)
                __hip_atomic_store(&h64g[(size_t)(t & 1) * 512 + row * 128 + ((jj + j) >> 2)],
                                   pk, __ATOMIC_RELAXED, __HIP_MEMORY_SCOPE_AGENT);
            asm volatile("s_waitcnt vmcnt(0)" ::: "memory");  // drain h stores (wave-local)
            if (tid == 0)
                __hip_atomic_store(&flg[k * 16], t + 1, __ATOMIC_RELAXED,
                                   __HIP_MEMORY_SCOPE_AGENT);
            if ((j & 3) == 0)   // lstm_out write off the sync path
                *(u64*)&out[((size_t)(b0 + row) * NL + t) * NH + jj + j] = pk;
        }
    }
}

// Fused: Q = x@Wm^T+bm (prologue), flash attention with decayed-causal scores,
// FF head relu(W@W1^T+b1)@W2^T+b2 (epilogue). 16-row q tiles, 512 threads.
__global__ __launch_bounds__(512) void k_attn(const float* __restrict__ x,
                                              const float* __restrict__ Wm,
                                              const float* __restrict__ bm,
                                              const u16* __restrict__ kv,
                                              const float* __restrict__ W1,
                                              const float* __restrict__ b1,
                                              const float* __restrict__ W2,
                                              const float* __restrict__ b2,
                                              float* __restrict__ outp) {
    __shared__ __align__(16) u16 Qs[16 * 520];
    __shared__ __align__(16) u16 Vt[512 * 40];
    __shared__ float Sbuf[16 * 33];
    __shared__ __align__(16) u16 Pbuf[16 * 40];
    __shared__ float alpha_s[16];
    __shared__ float l_s[16];
    int b = blockIdx.x, qt = blockIdx.y;
    int tid = threadIdx.x, w = tid >> 6, l = tid & 63, quad = l >> 4, lane = l & 15;

    {   // prologue: Qs[16][512] = x_tile @ Wm^T + bm
        const float* xq = x + ((size_t)b * NL + qt * 16 + lane) * ND;
#pragma unroll
        for (int nt2 = 0; nt2 < 4; nt2++) {
            int n = (w * 4 + nt2) * 16 + lane;
            const float* wmp = Wm + (size_t)n * ND;
            f32x4 aq = {};
#pragma unroll 4
            for (int kk = 0; kk < 16; kk++)
                aq = MF(cvt8(&xq[kk * 32 + quad * 8]), cvt8(&wmp[kk * 32 + quad * 8]), aq);
            float bmv = bm[n];
#pragma unroll
            for (int r = 0; r < 4; r++)
                Qs[(quad * 4 + r) * 520 + n] = f2b(aq[r] + bmv);
        }
    }
    float m_run = -30000.f, l_run = 0.f;
    f32x4 acc[4] = {};
    __syncthreads();

    int st_max = ((qt << 4) + 15) >> 5;
    for (int st = 0; st <= st_max; st++) {
        if (w < 2) {  // QK^T: S[16][32], waves 0..1
            int ni = w;
            f32x4 s = {};
            const u16* krow = kv + ((size_t)b * NL + st * 32 + ni * 16 + lane) * NH;
#pragma unroll 4
            for (int kk = 0; kk < 16; kk++)
                s = MF(*(bf16x8*)&Qs[lane * 520 + kk * 32 + quad * 8],
                       *(const bf16x8*)&krow[kk * 32 + quad * 8], s);
            int scol = st * 32 + ni * 16 + lane;
#pragma unroll
            for (int r = 0; r < 4; r++) {
                int trow = (qt << 4) + quad * 4 + r;
                int dt = trow - scol;
                float v = (dt < 0) ? -30000.f : s[r] * __expf(-0.6f * (float)dt);
                Sbuf[(quad * 4 + r) * 33 + ni * 16 + lane] = v;
            }
        } else if (w >= 4) {  // stage V^T[512][32]
            int t2 = tid & 255;
            int srow = t2 >> 3, dseg = t2 & 7;
            const u16* vsrc = kv + ((size_t)b * NL + st * 32 + srow) * NH + dseg * 64;
#pragma unroll
            for (int i = 0; i < 8; i++) {
                union { uint4 v; u16 h[8]; } u;
                u.v = *(const uint4*)&vsrc[i * 8];
                int d0 = dseg * 64 + i * 8;
#pragma unroll
                for (int j2 = 0; j2 < 8; j2++) Vt[(d0 + j2) * 40 + srow] = u.h[j2];
            }
        }
        __syncthreads();
        if (tid < 16) {  // online softmax
            int m = tid;
            float vmax = -30000.f;
#pragma unroll 8
            for (int n = 0; n < 32; n++) vmax = fmaxf(vmax, Sbuf[m * 33 + n]);
            float mnew = fmaxf(m_run, vmax);
            float al = __expf(m_run - mnew);
            float lsum = 0.f;
#pragma unroll 8
            for (int n = 0; n < 32; n++) {
                float p = __expf(Sbuf[m * 33 + n] - mnew);
                lsum += p;
                Pbuf[m * 40 + n] = f2b(p);
            }
            l_run = l_run * al + lsum;
            m_run = mnew;
            alpha_s[m] = al;
            l_s[m] = l_run;
        }
        __syncthreads();
        {   // PV
            float a0 = alpha_s[quad * 4 + 0];
            float a1 = alpha_s[quad * 4 + 1];
            float a2 = alpha_s[quad * 4 + 2];
            float a3 = alpha_s[quad * 4 + 3];
            bf16x8 afrag = *(bf16x8*)&Pbuf[lane * 40 + quad * 8];
#pragma unroll
            for (int di = 0; di < 4; di++) {
                int dtile = w * 4 + di;
                f32x4 c = acc[di];
                c[0] *= a0; c[1] *= a1; c[2] *= a2; c[3] *= a3;
                acc[di] = MF(afrag, *(bf16x8*)&Vt[(dtile * 16 + lane) * 40 + quad * 8], c);
            }
        }
        __syncthreads();
    }

    u16* Wt = Vt;   // weighted -> LDS
    {
        float li0 = 1.f / l_s[quad * 4 + 0];
        float li1 = 1.f / l_s[quad * 4 + 1];
        float li2 = 1.f / l_s[quad * 4 + 2];
        float li3 = 1.f / l_s[quad * 4 + 3];
#pragma unroll
        for (int di = 0; di < 4; di++) {
            int col = (w * 4 + di) * 16 + lane;
            Wt[(quad * 4 + 0) * 520 + col] = f2b(acc[di][0] * li0);
            Wt[(quad * 4 + 1) * 520 + col] = f2b(acc[di][1] * li1);
            Wt[(quad * 4 + 2) * 520 + col] = f2b(acc[di][2] * li2);
            Wt[(quad * 4 + 3) * 520 + col] = f2b(acc[di][3] * li3);
        }
    }
    __syncthreads();
    u16* H1 = Qs;
    {   // H1[16][256] = relu(Wt @ W1^T + b1)
#pragma unroll
        for (int nt2 = 0; nt2 < 2; nt2++) {
            int n = (w * 2 + nt2) * 16 + lane;
            const float* w1p = W1 + (size_t)n * ND;
            f32x4 a1 = {};
#pragma unroll 4
            for (int kk = 0; kk < 16; kk++)
                a1 = MF(*(bf16x8*)&Wt[lane * 520 + kk * 32 + quad * 8],
                        cvt8(&w1p[kk * 32 + quad * 8]), a1);
            float b1v = b1[n];
#pragma unroll
            for (int r = 0; r < 4; r++)
                H1[(quad * 4 + r) * 264 + n] = f2b(fmaxf(a1[r] + b1v, 0.f));
        }
    }
    __syncthreads();
    if (w < 7) {  // out[16][100] = H1 @ W2^T + b2
        int n = w * 16 + lane;
        int nc = n < NOUT ? n : NOUT - 1;
        const float* w2p = W2 + (size_t)nc * NFF;
        f32x4 a2 = {};
#pragma unroll
        for (int kk = 0; kk < 8; kk++)
            a2 = MF(*(bf16x8*)&H1[lane * 264 + kk * 32 + quad * 8],
                    cvt8(&w2p[kk * 32 + quad * 8]), a2);
        if (n < NOUT) {
            float b2v = b2[n];
#pragma unroll
            for (int r = 0; r < 4; r++)
                outp[((size_t)b * NL + (qt << 4) + quad * 4 + r) * NOUT + n] = a2[r] + b2v;
        }
    }
}

extern "C" void kernel_launch(void* const* d_in, const int* in_sizes, int n_in,
                              void* d_out, int out_size, void* d_ws, size_t ws_size,
                              hipStream_t stream) {
    const float* x        = (const float*)d_in[0];
    const int*   concepts = (const int*)d_in[1];
    const float* emb      = (const float*)d_in[2];
    const float* Wih      = (const float*)d_in[3];
    const float* Whh      = (const float*)d_in[4];
    const float* bih      = (const float*)d_in[5];
    const float* bhh      = (const float*)d_in[6];
    const float* Wm       = (const float*)d_in[7];
    const float* bm       = (const float*)d_in[8];
    const float* W1       = (const float*)d_in[9];
    const float* b1       = (const float*)d_in[10];
    const float* W2       = (const float*)d_in[11];
    const float* b2       = (const float*)d_in[12];
    float* outp = (float*)d_out;

    char* ws = (char*)d_ws;
    size_t off = 0;
    u16* lstm_out = (u16*)(ws + off); off += (size_t)NB * NL * NH * 2;   // 32 MB
    float* cbias  = (float*)(ws + off); off += (size_t)NB * G4 * 4;      // 256 KB
    u64* h64      = (u64*)(ws + off); off += (size_t)8 * 1024 * 8;       // 64 KB
    int* flags    = (int*)(ws + off); off += 8 * 32 * 16 * 4;            // 16 KB

    hipMemsetAsync(flags, 0, 8 * 32 * 16 * 4, stream);
    k_cbias<<<dim3(NB, G4 / 256), 256, 0, stream>>>(emb, concepts, Wih, bih, bhh, cbias);
    k_lstm<<<256, 256, 0, stream>>>(x, Wih, Whh, cbias, lstm_out, h64, flags);
    k_attn<<<dim3(NB, NL / 16), 512, 0, stream>>>(x, Wm, bm, lstm_out, W1, b1, W2, b2, outp);
}

// Round 5
// 2935.955 us; speedup vs baseline: 1.6031x; 1.1908x over previous
//
#include <hip/hip_runtime.h>
#include <hip/hip_bf16.h>
#include <stdint.h>

typedef unsigned short u16;
typedef unsigned int u32;
typedef unsigned long long u64;
typedef float f32x4 __attribute__((ext_vector_type(4)));
typedef short bf16x8 __attribute__((ext_vector_type(8)));
typedef unsigned u32x4 __attribute__((ext_vector_type(4)));   // native vector for asm 'v'

#define NB 32
#define NL 1024
#define ND 512
#define NH 512
#define G4 2048
#define NOUT 100
#define NFF 256
#define HSTR 528   // LDS row stride (halfwords): 264 dwords == 8 mod 32 -> uniform 2-way (free) a-frag reads

__device__ inline u16 f2b(float f) {
    union { float f; unsigned i; } c; c.f = f;
    unsigned i = c.i;
    return (u16)((i + 0x7FFFu + ((i >> 16) & 1u)) >> 16);
}
__device__ inline bf16x8 cvt8(const float* __restrict__ p) {
    float4 a = *(const float4*)p;
    float4 b = *(const float4*)(p + 4);
    bf16x8 r;
    u16* h = (u16*)&r;
    h[0] = f2b(a.x); h[1] = f2b(a.y); h[2] = f2b(a.z); h[3] = f2b(a.w);
    h[4] = f2b(b.x); h[5] = f2b(b.y); h[6] = f2b(b.z); h[7] = f2b(b.w);
    return r;
}
__device__ inline f32x4 MF(bf16x8 a, bf16x8 b, f32x4 c) {
    return __builtin_amdgcn_mfma_f32_16x16x32_bf16(a, b, c, 0, 0, 0);
}
__device__ inline float tanh_f(float x) {
    float xx = fminf(fmaxf(x, -15.f), 15.f);
    float e = __expf(2.f * xx);
    return (e - 1.f) / (e + 1.f);
}
__device__ inline float sigm_f(float x) { return 1.f / (1.f + __expf(-x)); }

// Single-instruction 16-B SYSTEM-coherent load/store (sc0 sc1 = scope >= agent,
// bypasses L1 and per-XCD L2 to the coherence point). One dwordx4 = one LLC
// request -> tag+payload move atomically within the aligned 16 B.
// Native u32x4 ext-vector satisfies the 'v' (VGPR-quad) constraint.
__device__ inline u32x4 ld_sc16(const u32x4* p) {
    u32x4 r;
    asm volatile("global_load_dwordx4 %0, %1, off sc0 sc1\n\t"
                 "s_waitcnt vmcnt(0)"
                 : "=&v"(r) : "v"(p) : "memory");
    return r;
}
__device__ inline void ld2_sc16(const u32x4* p1, const u32x4* p2, u32x4& r1, u32x4& r2) {
    asm volatile("global_load_dwordx4 %0, %2, off sc0 sc1\n\t"
                 "global_load_dwordx4 %1, %3, off sc0 sc1\n\t"
                 "s_waitcnt vmcnt(0)"
                 : "=&v"(r1), "=&v"(r2) : "v"(p1), "v"(p2) : "memory");
}
__device__ inline void st_sc16(u32x4* p, u32x4 v) {
    asm volatile("global_store_dwordx4 %0, %1, off sc0 sc1"
                 :: "v"(p), "v"(v) : "memory");
}

// cbias[b][r] = emb[concepts[b]] . Wih[r, 512:1024] + bih[r] + bhh[r]   (all fp32)
__global__ __launch_bounds__(256) void k_cbias(const float* __restrict__ emb,
                                               const int* __restrict__ concepts,
                                               const float* __restrict__ Wih,
                                               const float* __restrict__ bih,
                                               const float* __restrict__ bhh,
                                               float* __restrict__ cbias) {
    __shared__ float e[ND];
    int b = blockIdx.x;
    int r = blockIdx.y * 256 + threadIdx.x;
    int c = concepts[b];
    for (int i = threadIdx.x; i < ND; i += 256) e[i] = emb[c * ND + i];
    __syncthreads();
    const float* wrow = Wih + (size_t)r * 1024 + 512;
    float acc = 0.f;
#pragma unroll 4
    for (int k4 = 0; k4 < 128; k4++) {
        float4 wv = *(const float4*)&wrow[k4 * 4];
        acc += e[k4 * 4 + 0] * wv.x + e[k4 * 4 + 1] * wv.y +
               e[k4 * 4 + 2] * wv.z + e[k4 * 4 + 3] * wv.w;
    }
    cbias[b * G4 + r] = acc + bih[r] + bhh[r];
}

// Persistent LSTM, batch-split: 8 groups x 32 blocks; group g owns batch rows [4g,4g+4),
// block k owns h lanes [16k,16k+16) (64 gate rows; wave w = gate w).
// v6 = v5 with native-vector asm types (compile fix):
//  - h published as 16-B units {6 bf16 | u32 tag=t+1} (3 units per (producer,row));
//    consumers spin on a single ld_sc16 until tag==t (exact match => stale-safe).
//    One LLC round trip replaces v0's drain -> flag store -> poll -> bulk load chain.
//  - Cell phase distributed: wave w computes batch row w, publishes its own units.
//  - MFMA: 4 independent accumulator chains (kk%4), merged once -> 4-deep dep chains.
//  - x[t+2] prefetch issued after barrier (C); commit at top of next iteration.
//  - Weights in registers + HSTR=528 (v3-validated: conflicts 1.38e8 -> 4.2e6).
//  - Spin is guard-bounded (~0.5 s) so any visibility bug fails the bench instead of
//    hanging the container.
__global__ __launch_bounds__(256, 1) void k_lstm(const float* __restrict__ x,
                                                 const float* __restrict__ Wih,
                                                 const float* __restrict__ Whh,
                                                 const float* __restrict__ cbias,
                                                 u16* __restrict__ out,
                                                 u32x4* __restrict__ hx) {
    __shared__ __align__(16) u16 hsb[4 * HSTR];         // h[t-1] tile, bf16
    __shared__ __align__(16) u16 xb[2][4 * HSTR];       // x double buffer, bf16
    __shared__ float gbuf[4 * 68];
    __shared__ float cb_lds[4 * 64];
    int g = blockIdx.x & 7, k = blockIdx.x >> 3;
    int tid = threadIdx.x;
    int w = tid >> 6, l = tid & 63, quad = l >> 4, lane = l & 15;
    int jj = k * 16;
    int b0 = g * 4;
    int rr = w, f0 = l * 8;

    // ---- init: weights -> registers (fp32->bf16 fragments), cbias, x[0] -> LDS
    bf16x8 bwx[16], bwh[16];
    {
        int n = l & 15, q4 = l >> 4;
        const float* wsrc = Wih + (size_t)(w * 512 + jj + n) * 1024 + q4 * 8;  // x-part
        const float* hsrc = Whh + (size_t)(w * 512 + jj + n) * 512 + q4 * 8;
#pragma unroll
        for (int kk = 0; kk < 16; kk++) {
            bwx[kk] = cvt8(wsrc + kk * 32);
            bwh[kk] = cvt8(hsrc + kk * 32);
        }
        cb_lds[tid] = cbias[(size_t)(b0 + (tid >> 6)) * G4 +
                            (((tid >> 4) & 3) * 512) + jj + (tid & 15)];
        *(bf16x8*)&xb[0][rr * HSTR + f0] = cvt8(&x[((size_t)(b0 + rr) * NL) * ND + f0]);
    }

    // ---- consumer precompute: 384 units (32 producers x 4 rows x 3 units), <=2/thread.
    // unit u: p=u/12, r=(u%12)/3, s=u%3; payload = h[p*16+s*6 .. ] (s==2: 4 vals)
    u32x4* hxg = hx + (size_t)g * 768;               // per-group: 2 parity x 384 units
    int u1 = tid;
    int rm1 = u1 % 12;
    int lo1 = (rm1 / 3) * HSTR + (u1 / 12) * 16 + (rm1 % 3) * 6;   // hsb halfword offset
    int s1u = rm1 % 3;
    const u32x4* a1base = hxg + u1;
    bool two = (tid < 128);
    int u2 = 256 + tid;
    int rm2 = u2 % 12;
    int lo2 = (rm2 / 3) * HSTR + (u2 / 12) * 16 + (rm2 % 3) * 6;
    int s2u = rm2 % 3;
    const u32x4* a2base = hxg + u2;
    u32x4* myst = hxg + k * 12 + w * 3;              // producer units (this wave = row w)

    // preload x[1] into prefetch regs (committed at top of iter 0)
    float4 pa, pb;
    {
        const float* px = &x[((size_t)(b0 + rr) * NL + 1) * ND + f0];
        pa = *(const float4*)px; pb = *(const float4*)(px + 4);
    }
    __syncthreads();

    float c_reg = 0.f;   // cell state for (row w, col jj + (l&15)); dup across quads

    for (int t = 0; t < NL; t++) {
        // ---- commit x[t+1] (loads issued one full iteration ago -> no stall)
        if (t + 1 < NL) {
            bf16x8 xv; u16* hh = (u16*)&xv;
            hh[0] = f2b(pa.x); hh[1] = f2b(pa.y); hh[2] = f2b(pa.z); hh[3] = f2b(pa.w);
            hh[4] = f2b(pb.x); hh[5] = f2b(pb.y); hh[6] = f2b(pb.z); hh[7] = f2b(pb.w);
            *(bf16x8*)&xb[(t + 1) & 1][rr * HSTR + f0] = xv;
        }
        // ---- x-part MFMA, 4 independent accumulator chains
        f32x4 ac0 = {}, ac1 = {}, ac2 = {}, ac3 = {};
#pragma unroll
        for (int kk = 0; kk < 16; kk += 4) {
            const u16* xbp = &xb[t & 1][(lane & 3) * HSTR + quad * 8];
            ac0 = MF(*(bf16x8*)&xbp[(kk + 0) * 32], bwx[kk + 0], ac0);
            ac1 = MF(*(bf16x8*)&xbp[(kk + 1) * 32], bwx[kk + 1], ac1);
            ac2 = MF(*(bf16x8*)&xbp[(kk + 2) * 32], bwx[kk + 2], ac2);
            ac3 = MF(*(bf16x8*)&xbp[(kk + 3) * 32], bwx[kk + 3], ac3);
        }
        if (t > 0) {
            // ---- consumer: tagged spin (one LLC round trip when producers are ahead)
            int poff = ((t - 1) & 1) * 384;
            const u32x4* A1p = a1base + poff;
            const u32x4* A2p = a2base + poff;
            u32x4 A1 = {}, A2 = {};
            if (two) ld2_sc16(A1p, A2p, A1, A2);
            else     A1 = ld_sc16(A1p);
            int guard = 0;
            while (A1.w != (u32)t) {
                if (++guard > (1 << 22)) break;   // hang-proof: ~0.5 s cap
                __builtin_amdgcn_s_sleep(1);
                A1 = ld_sc16(A1p);
            }
            if (two) {
                guard = 0;
                while (A2.w != (u32)t) {
                    if (++guard > (1 << 22)) break;
                    __builtin_amdgcn_s_sleep(1);
                    A2 = ld_sc16(A2p);
                }
            }
            *(u32*)&hsb[lo1] = A1.x; *(u32*)&hsb[lo1 + 2] = A1.y;
            if (s1u < 2) *(u32*)&hsb[lo1 + 4] = A1.z;
            if (two) {
                *(u32*)&hsb[lo2] = A2.x; *(u32*)&hsb[lo2 + 2] = A2.y;
                if (s2u < 2) *(u32*)&hsb[lo2 + 4] = A2.z;
            }
            __syncthreads();   // (C) hsb ready
        }
        // ---- issue x[t+2] prefetch (post-C: spin's vmcnt(0) never waits on these)
        if (t + 2 < NL) {
            const float* px = &x[((size_t)(b0 + rr) * NL + (t + 2)) * ND + f0];
            pa = *(const float4*)px; pb = *(const float4*)(px + 4);
        }
        if (t > 0) {
            // ---- h-part MFMA into the same 4 chains
#pragma unroll
            for (int kk = 0; kk < 16; kk += 4) {
                const u16* hbp = &hsb[(lane & 3) * HSTR + quad * 8];
                ac0 = MF(*(bf16x8*)&hbp[(kk + 0) * 32], bwh[kk + 0], ac0);
                ac1 = MF(*(bf16x8*)&hbp[(kk + 1) * 32], bwh[kk + 1], ac1);
                ac2 = MF(*(bf16x8*)&hbp[(kk + 2) * 32], bwh[kk + 2], ac2);
                ac3 = MF(*(bf16x8*)&hbp[(kk + 3) * 32], bwh[kk + 3], ac3);
            }
        }
        f32x4 acc = (ac0 + ac1) + (ac2 + ac3);
        if (quad == 0) {   // C rows m=0..3 live in quad 0 regs (gate w, cols jj+lane)
#pragma unroll
            for (int r = 0; r < 4; r++)
                gbuf[r * 68 + w * 16 + lane] = acc[r];
        }
        __syncthreads();   // (B)
        {   // ---- cell: wave w owns batch row w; all 64 lanes compute (j dup x4 quads)
            int j = l & 15;
            float gi = gbuf[w * 68 + 0 * 16 + j] + cb_lds[w * 64 + 0 * 16 + j];
            float gf = gbuf[w * 68 + 1 * 16 + j] + cb_lds[w * 64 + 1 * 16 + j];
            float gg = gbuf[w * 68 + 2 * 16 + j] + cb_lds[w * 64 + 2 * 16 + j];
            float go = gbuf[w * 68 + 3 * 16 + j] + cb_lds[w * 64 + 3 * 16 + j];
            float iv = sigm_f(gi), fv = sigm_f(gf), ov = sigm_f(go);
            float gv = tanh_f(gg);
            c_reg = fv * c_reg + iv * gv;
            unsigned hb32 = (unsigned)f2b(ov * tanh_f(c_reg));
            // pack tagged units: builder lanes l=0..2 gather h[j'=l*6+i] (from lanes 0..15;
            // lanes 16,17 duplicate j=0,1 values -> safe sources for l=2's tail)
            unsigned t0 = __shfl(hb32, l * 6 + 0), t1 = __shfl(hb32, l * 6 + 1);
            unsigned t2 = __shfl(hb32, l * 6 + 2), t3 = __shfl(hb32, l * 6 + 3);
            unsigned t4 = __shfl(hb32, l * 6 + 4), t5 = __shfl(hb32, l * 6 + 5);
            if (l < 3) {
                u32x4 U;
                U.x = t0 | (t1 << 16);
                U.y = t2 | (t3 << 16);
                U.z = (l < 2) ? (t4 | (t5 << 16)) : 0u;
                U.w = (u32)(t + 1);
                st_sc16(myst + (t & 1) * 384 + l, U);
            }
            // lstm_out write (plain store; flushed at kernel boundary)
            unsigned v1 = __shfl_down(hb32, 1);
            unsigned v2 = __shfl_down(hb32, 2);
            unsigned v3 = __shfl_down(hb32, 3);
            if (l < 16 && (l & 3) == 0) {
                u64 pk = (u64)hb32 | ((u64)v1 << 16) | ((u64)v2 << 32) | ((u64)v3 << 48);
                *(u64*)&out[((size_t)(b0 + w) * NL + t) * NH + jj + l] = pk;
            }
        }
    }
}

// Fused: Q = x@Wm^T+bm (prologue), flash attention with decayed-causal scores,
// FF head relu(W@W1^T+b1)@W2^T+b2 (epilogue). 16-row q tiles, 512 threads.
__global__ __launch_bounds__(512) void k_attn(const float* __restrict__ x,
                                              const float* __restrict__ Wm,
                                              const float* __restrict__ bm,
                                              const u16* __restrict__ kv,
                                              const float* __restrict__ W1,
                                              const float* __restrict__ b1,
                                              const float* __restrict__ W2,
                                              const float* __restrict__ b2,
                                              float* __restrict__ outp) {
    __shared__ __align__(16) u16 Qs[16 * 520];
    __shared__ __align__(16) u16 Vt[512 * 40];
    __shared__ float Sbuf[16 * 33];
    __shared__ __align__(16) u16 Pbuf[16 * 40];
    __shared__ float alpha_s[16];
    __shared__ float l_s[16];
    int b = blockIdx.x, qt = blockIdx.y;
    int tid = threadIdx.x, w = tid >> 6, l = tid & 63, quad = l >> 4, lane = l & 15;

    {   // prologue: Qs[16][512] = x_tile @ Wm^T + bm
        const float* xq = x + ((size_t)b * NL + qt * 16 + lane) * ND;
#pragma unroll
        for (int nt2 = 0; nt2 < 4; nt2++) {
            int n = (w * 4 + nt2) * 16 + lane;
            const float* wmp = Wm + (size_t)n * ND;
            f32x4 aq = {};
#pragma unroll 4
            for (int kk = 0; kk < 16; kk++)
                aq = MF(cvt8(&xq[kk * 32 + quad * 8]), cvt8(&wmp[kk * 32 + quad * 8]), aq);
            float bmv = bm[n];
#pragma unroll
            for (int r = 0; r < 4; r++)
                Qs[(quad * 4 + r) * 520 + n] = f2b(aq[r] + bmv);
        }
    }
    float m_run = -30000.f, l_run = 0.f;
    f32x4 acc[4] = {};
    __syncthreads();

    int st_max = ((qt << 4) + 15) >> 5;
    for (int st = 0; st <= st_max; st++) {
        if (w < 2) {  // QK^T: S[16][32], waves 0..1
            int ni = w;
            f32x4 s = {};
            const u16* krow = kv + ((size_t)b * NL + st * 32 + ni * 16 + lane) * NH;
#pragma unroll 4
            for (int kk = 0; kk < 16; kk++)
                s = MF(*(bf16x8*)&Qs[lane * 520 + kk * 32 + quad * 8],
                       *(const bf16x8*)&krow[kk * 32 + quad * 8], s);
            int scol = st * 32 + ni * 16 + lane;
#pragma unroll
            for (int r = 0; r < 4; r++) {
                int trow = (qt << 4) + quad * 4 + r;
                int dt = trow - scol;
                float v = (dt < 0) ? -30000.f : s[r] * __expf(-0.6f * (float)dt);
                Sbuf[(quad * 4 + r) * 33 + ni * 16 + lane] = v;
            }
        } else if (w >= 4) {  // stage V^T[512][32]
            int t2 = tid & 255;
            int srow = t2 >> 3, dseg = t2 & 7;
            const u16* vsrc = kv + ((size_t)b * NL + st * 32 + srow) * NH + dseg * 64;
#pragma unroll
            for (int i = 0; i < 8; i++) {
                union { uint4 v; u16 h[8]; } u;
                u.v = *(const uint4*)&vsrc[i * 8];
                int d0 = dseg * 64 + i * 8;
#pragma unroll
                for (int j2 = 0; j2 < 8; j2++) Vt[(d0 + j2) * 40 + srow] = u.h[j2];
            }
        }
        __syncthreads();
        if (tid < 16) {  // online softmax
            int m = tid;
            float vmax = -30000.f;
#pragma unroll 8
            for (int n = 0; n < 32; n++) vmax = fmaxf(vmax, Sbuf[m * 33 + n]);
            float mnew = fmaxf(m_run, vmax);
            float al = __expf(m_run - mnew);
            float lsum = 0.f;
#pragma unroll 8
            for (int n = 0; n < 32; n++) {
                float p = __expf(Sbuf[m * 33 + n] - mnew);
                lsum += p;
                Pbuf[m * 40 + n] = f2b(p);
            }
            l_run = l_run * al + lsum;
            m_run = mnew;
            alpha_s[m] = al;
            l_s[m] = l_run;
        }
        __syncthreads();
        {   // PV
            float a0 = alpha_s[quad * 4 + 0];
            float a1 = alpha_s[quad * 4 + 1];
            float a2 = alpha_s[quad * 4 + 2];
            float a3 = alpha_s[quad * 4 + 3];
            bf16x8 afrag = *(bf16x8*)&Pbuf[lane * 40 + quad * 8];
#pragma unroll
            for (int di = 0; di < 4; di++) {
                int dtile = w * 4 + di;
                f32x4 c = acc[di];
                c[0] *= a0; c[1] *= a1; c[2] *= a2; c[3] *= a3;
                acc[di] = MF(afrag, *(bf16x8*)&Vt[(dtile * 16 + lane) * 40 + quad * 8], c);
            }
        }
        __syncthreads();
    }

    u16* Wt = Vt;   // weighted -> LDS
    {
        float li0 = 1.f / l_s[quad * 4 + 0];
        float li1 = 1.f / l_s[quad * 4 + 1];
        float li2 = 1.f / l_s[quad * 4 + 2];
        float li3 = 1.f / l_s[quad * 4 + 3];
#pragma unroll
        for (int di = 0; di < 4; di++) {
            int col = (w * 4 + di) * 16 + lane;
            Wt[(quad * 4 + 0) * 520 + col] = f2b(acc[di][0] * li0);
            Wt[(quad * 4 + 1) * 520 + col] = f2b(acc[di][1] * li1);
            Wt[(quad * 4 + 2) * 520 + col] = f2b(acc[di][2] * li2);
            Wt[(quad * 4 + 3) * 520 + col] = f2b(acc[di][3] * li3);
        }
    }
    __syncthreads();
    u16* H1 = Qs;
    {   // H1[16][256] = relu(Wt @ W1^T + b1)
#pragma unroll
        for (int nt2 = 0; nt2 < 2; nt2++) {
            int n = (w * 2 + nt2) * 16 + lane;
            const float* w1p = W1 + (size_t)n * ND;
            f32x4 a1 = {};
#pragma unroll 4
            for (int kk = 0; kk < 16; kk++)
                a1 = MF(*(bf16x8*)&Wt[lane * 520 + kk * 32 + quad * 8],
                        cvt8(&w1p[kk * 32 + quad * 8]), a1);
            float b1v = b1[n];
#pragma unroll
            for (int r = 0; r < 4; r++)
                H1[(quad * 4 + r) * 264 + n] = f2b(fmaxf(a1[r] + b1v, 0.f));
        }
    }
    __syncthreads();
    if (w < 7) {  // out[16][100] = H1 @ W2^T + b2
        int n = w * 16 + lane;
        int nc = n < NOUT ? n : NOUT - 1;
        const float* w2p = W2 + (size_t)nc * NFF;
        f32x4 a2 = {};
#pragma unroll
        for (int kk = 0; kk < 8; kk++)
            a2 = MF(*(bf16x8*)&H1[lane * 264 + kk * 32 + quad * 8],
                    cvt8(&w2p[kk * 32 + quad * 8]), a2);
        if (n < NOUT) {
            float b2v = b2[n];
#pragma unroll
            for (int r = 0; r < 4; r++)
                outp[((size_t)b * NL + (qt << 4) + quad * 4 + r) * NOUT + n] = a2[r] + b2v;
        }
    }
}

extern "C" void kernel_launch(void* const* d_in, const int* in_sizes, int n_in,
                              void* d_out, int out_size, void* d_ws, size_t ws_size,
                              hipStream_t stream) {
    const float* x        = (const float*)d_in[0];
    const int*   concepts = (const int*)d_in[1];
    const float* emb      = (const float*)d_in[2];
    const float* Wih      = (const float*)d_in[3];
    const float* Whh      = (const float*)d_in[4];
    const float* bih      = (const float*)d_in[5];
    const float* bhh      = (const float*)d_in[6];
    const float* Wm       = (const float*)d_in[7];
    const float* bm       = (const float*)d_in[8];
    const float* W1       = (const float*)d_in[9];
    const float* b1       = (const float*)d_in[10];
    const float* W2       = (const float*)d_in[11];
    const float* b2       = (const float*)d_in[12];
    float* outp = (float*)d_out;

    char* ws = (char*)d_ws;
    size_t off = 0;
    u16* lstm_out = (u16*)(ws + off); off += (size_t)NB * NL * NH * 2;   // 32 MB
    float* cbias  = (float*)(ws + off); off += (size_t)NB * G4 * 4;      // 256 KB
    u32x4* hx     = (u32x4*)(ws + off); off += (size_t)8 * 768 * 16;     // 96 KB tagged h units

    (void)hipMemsetAsync(hx, 0, (size_t)8 * 768 * 16, stream);  // tags=0 != any expected tag
    k_cbias<<<dim3(NB, G4 / 256), 256, 0, stream>>>(emb, concepts, Wih, bih, bhh, cbias);
    k_lstm<<<256, 256, 0, stream>>>(x, Wih, Whh, cbias, lstm_out, hx);
    k_attn<<<dim3(NB, NL / 16), 512, 0, stream>>>(x, Wm, bm, lstm_out, W1, b1, W2, b2, outp);
}

// Round 6
// 2418.592 us; speedup vs baseline: 1.9460x; 1.2139x over previous
//
#include <hip/hip_runtime.h>
#include <hip/hip_bf16.h>
#include <stdint.h>

typedef unsigned short u16;
typedef unsigned int u32;
typedef unsigned long long u64;
typedef float f32x4 __attribute__((ext_vector_type(4)));
typedef short bf16x8 __attribute__((ext_vector_type(8)));
typedef unsigned u32x4 __attribute__((ext_vector_type(4)));   // native vector for asm 'v'

#define NB 32
#define NL 1024
#define ND 512
#define NH 512
#define G4 2048
#define NOUT 100
#define NFF 256
#define HSTR 528   // LDS row stride (halfwords): 264 dwords == 8 mod 32 -> uniform 2-way (free) a-frag reads

__device__ inline u16 f2b(float f) {
    union { float f; unsigned i; } c; c.f = f;
    unsigned i = c.i;
    return (u16)((i + 0x7FFFu + ((i >> 16) & 1u)) >> 16);
}
__device__ inline bf16x8 cvt8(const float* __restrict__ p) {
    float4 a = *(const float4*)p;
    float4 b = *(const float4*)(p + 4);
    bf16x8 r;
    u16* h = (u16*)&r;
    h[0] = f2b(a.x); h[1] = f2b(a.y); h[2] = f2b(a.z); h[3] = f2b(a.w);
    h[4] = f2b(b.x); h[5] = f2b(b.y); h[6] = f2b(b.z); h[7] = f2b(b.w);
    return r;
}
__device__ inline f32x4 MF(bf16x8 a, bf16x8 b, f32x4 c) {
    return __builtin_amdgcn_mfma_f32_16x16x32_bf16(a, b, c, 0, 0, 0);
}
__device__ inline float tanh_f(float x) {
    float xx = fminf(fmaxf(x, -15.f), 15.f);
    float e = __expf(2.f * xx);
    return (e - 1.f) / (e + 1.f);
}
__device__ inline float sigm_f(float x) { return 1.f / (1.f + __expf(-x)); }

// 16-B SYSTEM-coherent load/store (sc0 sc1: scope >= agent, to the coherence point).
// One dwordx4 = one LLC request -> tag+payload move atomically within the aligned 16 B.
__device__ inline u32x4 ld_sc16(const u32x4* p) {
    u32x4 r;
    asm volatile("global_load_dwordx4 %0, %1, off sc0 sc1\n\t"
                 "s_waitcnt vmcnt(0)"
                 : "=&v"(r) : "v"(p) : "memory");
    return r;
}
// split issue/wait pair: issue early, overlap latency under the x-MFMA, wait late.
__device__ inline void ld1_issue(const u32x4* p, u32x4& r) {
    asm volatile("global_load_dwordx4 %0, %1, off sc0 sc1"
                 : "=&v"(r) : "v"(p) : "memory");
}
__device__ inline void ld2_issue(const u32x4* p1, const u32x4* p2, u32x4& r1, u32x4& r2) {
    asm volatile("global_load_dwordx4 %0, %2, off sc0 sc1\n\t"
                 "global_load_dwordx4 %1, %3, off sc0 sc1"
                 : "=&v"(r1), "=&v"(r2) : "v"(p1), "v"(p2) : "memory");
}
__device__ inline void wait_vm1(u32x4& r1) {
    asm volatile("s_waitcnt vmcnt(0)" : "+v"(r1) :: "memory");
}
__device__ inline void wait_vm2(u32x4& r1, u32x4& r2) {
    asm volatile("s_waitcnt vmcnt(0)" : "+v"(r1), "+v"(r2) :: "memory");
}
__device__ inline void st_sc16(u32x4* p, u32x4 v) {
    asm volatile("global_store_dwordx4 %0, %1, off sc0 sc1"
                 :: "v"(p), "v"(v) : "memory");
}

// f32 -> bf16 pre-cast (weights for k_attn): one quad per thread.
__global__ __launch_bounds__(256) void k_wcast(const float* __restrict__ s,
                                               u16* __restrict__ d, int n4) {
    int i = blockIdx.x * 256 + threadIdx.x;
    if (i >= n4) return;
    float4 v = *(const float4*)&s[(size_t)i * 4];
    u64 pk = (u64)f2b(v.x) | ((u64)f2b(v.y) << 16) |
             ((u64)f2b(v.z) << 32) | ((u64)f2b(v.w) << 48);
    *(u64*)&d[(size_t)i * 4] = pk;
}

// cbias[b][r] = emb[concepts[b]] . Wih[r, 512:1024] + bih[r] + bhh[r]   (all fp32)
__global__ __launch_bounds__(256) void k_cbias(const float* __restrict__ emb,
                                               const int* __restrict__ concepts,
                                               const float* __restrict__ Wih,
                                               const float* __restrict__ bih,
                                               const float* __restrict__ bhh,
                                               float* __restrict__ cbias) {
    __shared__ float e[ND];
    int b = blockIdx.x;
    int r = blockIdx.y * 256 + threadIdx.x;
    int c = concepts[b];
    for (int i = threadIdx.x; i < ND; i += 256) e[i] = emb[c * ND + i];
    __syncthreads();
    const float* wrow = Wih + (size_t)r * 1024 + 512;
    float acc = 0.f;
#pragma unroll 4
    for (int k4 = 0; k4 < 128; k4++) {
        float4 wv = *(const float4*)&wrow[k4 * 4];
        acc += e[k4 * 4 + 0] * wv.x + e[k4 * 4 + 1] * wv.y +
               e[k4 * 4 + 2] * wv.z + e[k4 * 4 + 3] * wv.w;
    }
    cbias[b * G4 + r] = acc + bih[r] + bhh[r];
}

// Persistent LSTM, batch-split: 8 groups x 32 blocks; group g owns batch rows [4g,4g+4),
// block k owns h lanes [16k,16k+16) (64 gate rows; wave w = gate w).
// v7 = v6 (1930 us measured) + early spin-load issue:
//  - Tagged h exchange: 16-B units {6 bf16 | u32 tag=t+1}, system-coherent; consumers
//    spin until tag==t. One LLC round trip (v6 A/B: 2464 -> 1930 us vs flag protocol).
//  - NEW: spin loads ISSUED right after x-commit, WAITED after the x-MFMA -> the ~500 cy
//    LLC load latency overlaps the ~400 cy x-MFMA phase (no vmem ops in between, so the
//    vmcnt(0) waits only on these 2 loads). "+v" ties the tag check after the wait.
//  - Cell distributed: wave w computes batch row w, publishes its own units.
//  - 4 independent MFMA accumulator chains; weights in registers; HSTR=528.
//  - Spin guard-bounded (~0.5 s) so a visibility bug fails the bench, never hangs.
__global__ __launch_bounds__(256, 1) void k_lstm(const float* __restrict__ x,
                                                 const float* __restrict__ Wih,
                                                 const float* __restrict__ Whh,
                                                 const float* __restrict__ cbias,
                                                 u16* __restrict__ out,
                                                 u32x4* __restrict__ hx) {
    __shared__ __align__(16) u16 hsb[4 * HSTR];         // h[t-1] tile, bf16
    __shared__ __align__(16) u16 xb[2][4 * HSTR];       // x double buffer, bf16
    __shared__ float gbuf[4 * 68];
    __shared__ float cb_lds[4 * 64];
    int g = blockIdx.x & 7, k = blockIdx.x >> 3;
    int tid = threadIdx.x;
    int w = tid >> 6, l = tid & 63, quad = l >> 4, lane = l & 15;
    int jj = k * 16;
    int b0 = g * 4;
    int rr = w, f0 = l * 8;

    // ---- init: weights -> registers (fp32->bf16 fragments), cbias, x[0] -> LDS
    bf16x8 bwx[16], bwh[16];
    {
        int n = l & 15, q4 = l >> 4;
        const float* wsrc = Wih + (size_t)(w * 512 + jj + n) * 1024 + q4 * 8;  // x-part
        const float* hsrc = Whh + (size_t)(w * 512 + jj + n) * 512 + q4 * 8;
#pragma unroll
        for (int kk = 0; kk < 16; kk++) {
            bwx[kk] = cvt8(wsrc + kk * 32);
            bwh[kk] = cvt8(hsrc + kk * 32);
        }
        cb_lds[tid] = cbias[(size_t)(b0 + (tid >> 6)) * G4 +
                            (((tid >> 4) & 3) * 512) + jj + (tid & 15)];
        *(bf16x8*)&xb[0][rr * HSTR + f0] = cvt8(&x[((size_t)(b0 + rr) * NL) * ND + f0]);
    }

    // ---- consumer precompute: 384 units (32 producers x 4 rows x 3 units), <=2/thread.
    // unit u: p=u/12, r=(u%12)/3, s=u%3; payload = h[p*16+s*6 .. ] (s==2: 4 vals)
    u32x4* hxg = hx + (size_t)g * 768;               // per-group: 2 parity x 384 units
    int u1 = tid;
    int rm1 = u1 % 12;
    int lo1 = (rm1 / 3) * HSTR + (u1 / 12) * 16 + (rm1 % 3) * 6;   // hsb halfword offset
    int s1u = rm1 % 3;
    const u32x4* a1base = hxg + u1;
    bool two = (tid < 128);
    int u2 = 256 + tid;
    int rm2 = u2 % 12;
    int lo2 = (rm2 / 3) * HSTR + (u2 / 12) * 16 + (rm2 % 3) * 6;
    int s2u = rm2 % 3;
    const u32x4* a2base = hxg + u2;
    u32x4* myst = hxg + k * 12 + w * 3;              // producer units (this wave = row w)

    // preload x[1] into prefetch regs (committed at top of iter 0)
    float4 pa, pb;
    {
        const float* px = &x[((size_t)(b0 + rr) * NL + 1) * ND + f0];
        pa = *(const float4*)px; pb = *(const float4*)(px + 4);
    }
    __syncthreads();

    float c_reg = 0.f;   // cell state for (row w, col jj + (l&15)); dup across quads

    for (int t = 0; t < NL; t++) {
        // ---- commit x[t+1] (loads issued one full iteration ago -> no stall)
        if (t + 1 < NL) {
            bf16x8 xv; u16* hh = (u16*)&xv;
            hh[0] = f2b(pa.x); hh[1] = f2b(pa.y); hh[2] = f2b(pa.z); hh[3] = f2b(pa.w);
            hh[4] = f2b(pb.x); hh[5] = f2b(pb.y); hh[6] = f2b(pb.z); hh[7] = f2b(pb.w);
            *(bf16x8*)&xb[(t + 1) & 1][rr * HSTR + f0] = xv;
        }
        // ---- issue spin loads EARLY (latency hides under x-MFMA)
        u32x4 A1 = {}, A2 = {};
        const u32x4* A1p = a1base;
        const u32x4* A2p = a2base;
        if (t > 0) {
            int poff = ((t - 1) & 1) * 384;
            A1p = a1base + poff;
            A2p = a2base + poff;
            if (two) ld2_issue(A1p, A2p, A1, A2);
            else     ld1_issue(A1p, A1);
        }
        // ---- x-part MFMA, 4 independent accumulator chains (LDS/lgkm only)
        f32x4 ac0 = {}, ac1 = {}, ac2 = {}, ac3 = {};
#pragma unroll
        for (int kk = 0; kk < 16; kk += 4) {
            const u16* xbp = &xb[t & 1][(lane & 3) * HSTR + quad * 8];
            ac0 = MF(*(bf16x8*)&xbp[(kk + 0) * 32], bwx[kk + 0], ac0);
            ac1 = MF(*(bf16x8*)&xbp[(kk + 1) * 32], bwx[kk + 1], ac1);
            ac2 = MF(*(bf16x8*)&xbp[(kk + 2) * 32], bwx[kk + 2], ac2);
            ac3 = MF(*(bf16x8*)&xbp[(kk + 3) * 32], bwx[kk + 3], ac3);
        }
        if (t > 0) {
            // ---- wait + tagged spin (first check usually fresh: load overlapped MFMA)
            if (two) wait_vm2(A1, A2); else wait_vm1(A1);
            __builtin_amdgcn_sched_barrier(0);
            int guard = 0;
            while (A1.w != (u32)t) {
                if (++guard > (1 << 22)) break;   // hang-proof: ~0.5 s cap
                __builtin_amdgcn_s_sleep(1);
                A1 = ld_sc16(A1p);
            }
            if (two) {
                guard = 0;
                while (A2.w != (u32)t) {
                    if (++guard > (1 << 22)) break;
                    __builtin_amdgcn_s_sleep(1);
                    A2 = ld_sc16(A2p);
                }
            }
            *(u32*)&hsb[lo1] = A1.x; *(u32*)&hsb[lo1 + 2] = A1.y;
            if (s1u < 2) *(u32*)&hsb[lo1 + 4] = A1.z;
            if (two) {
                *(u32*)&hsb[lo2] = A2.x; *(u32*)&hsb[lo2 + 2] = A2.y;
                if (s2u < 2) *(u32*)&hsb[lo2 + 4] = A2.z;
            }
            __syncthreads();   // (C) hsb ready
        }
        // ---- issue x[t+2] prefetch (post-C: spin's vmcnt(0) never waits on these)
        if (t + 2 < NL) {
            const float* px = &x[((size_t)(b0 + rr) * NL + (t + 2)) * ND + f0];
            pa = *(const float4*)px; pb = *(const float4*)(px + 4);
        }
        if (t > 0) {
            // ---- h-part MFMA into the same 4 chains
#pragma unroll
            for (int kk = 0; kk < 16; kk += 4) {
                const u16* hbp = &hsb[(lane & 3) * HSTR + quad * 8];
                ac0 = MF(*(bf16x8*)&hbp[(kk + 0) * 32], bwh[kk + 0], ac0);
                ac1 = MF(*(bf16x8*)&hbp[(kk + 1) * 32], bwh[kk + 1], ac1);
                ac2 = MF(*(bf16x8*)&hbp[(kk + 2) * 32], bwh[kk + 2], ac2);
                ac3 = MF(*(bf16x8*)&hbp[(kk + 3) * 32], bwh[kk + 3], ac3);
            }
        }
        f32x4 acc = (ac0 + ac1) + (ac2 + ac3);
        if (quad == 0) {   // C rows m=0..3 live in quad 0 regs (gate w, cols jj+lane)
#pragma unroll
            for (int r = 0; r < 4; r++)
                gbuf[r * 68 + w * 16 + lane] = acc[r];
        }
        __syncthreads();   // (B)
        {   // ---- cell: wave w owns batch row w; all 64 lanes compute (j dup x4 quads)
            int j = l & 15;
            float gi = gbuf[w * 68 + 0 * 16 + j] + cb_lds[w * 64 + 0 * 16 + j];
            float gf = gbuf[w * 68 + 1 * 16 + j] + cb_lds[w * 64 + 1 * 16 + j];
            float gg = gbuf[w * 68 + 2 * 16 + j] + cb_lds[w * 64 + 2 * 16 + j];
            float go = gbuf[w * 68 + 3 * 16 + j] + cb_lds[w * 64 + 3 * 16 + j];
            float iv = sigm_f(gi), fv = sigm_f(gf), ov = sigm_f(go);
            float gv = tanh_f(gg);
            c_reg = fv * c_reg + iv * gv;
            unsigned hb32 = (unsigned)f2b(ov * tanh_f(c_reg));
            // pack tagged units: builder lanes l=0..2 gather h[j'=l*6+i] (from lanes 0..15;
            // lanes 16,17 duplicate j=0,1 values -> safe sources for l=2's tail)
            unsigned t0 = __shfl(hb32, l * 6 + 0), t1 = __shfl(hb32, l * 6 + 1);
            unsigned t2 = __shfl(hb32, l * 6 + 2), t3 = __shfl(hb32, l * 6 + 3);
            unsigned t4 = __shfl(hb32, l * 6 + 4), t5 = __shfl(hb32, l * 6 + 5);
            if (l < 3) {
                u32x4 U;
                U.x = t0 | (t1 << 16);
                U.y = t2 | (t3 << 16);
                U.z = (l < 2) ? (t4 | (t5 << 16)) : 0u;
                U.w = (u32)(t + 1);
                st_sc16(myst + (t & 1) * 384 + l, U);
            }
            // lstm_out write (plain store; flushed at kernel boundary)
            unsigned v1 = __shfl_down(hb32, 1);
            unsigned v2 = __shfl_down(hb32, 2);
            unsigned v3 = __shfl_down(hb32, 3);
            if (l < 16 && (l & 3) == 0) {
                u64 pk = (u64)hb32 | ((u64)v1 << 16) | ((u64)v2 << 32) | ((u64)v3 << 48);
                *(u64*)&out[((size_t)(b0 + w) * NL + t) * NH + jj + l] = pk;
            }
        }
    }
}

// Fused: Q = x@Wm^T+bm (prologue), flash attention with decayed-causal scores,
// FF head relu(W@W1^T+b1)@W2^T+b2 (epilogue). 16-row q tiles, 512 threads.
// v7: bf16 pre-cast weights (Wmb/W1b/W2b) -> no per-block cvt8 of weights; x fragment
// converted ONCE per kk (loop swap, 4x fewer cvt8); wave-parallel online softmax
// (64 lanes, 4 lanes/row, shfl_xor reduce) replacing the 16-thread serial loop.
__global__ __launch_bounds__(512) void k_attn(const float* __restrict__ x,
                                              const u16* __restrict__ Wmb,
                                              const float* __restrict__ bm,
                                              const u16* __restrict__ kv,
                                              const u16* __restrict__ W1b,
                                              const float* __restrict__ b1,
                                              const u16* __restrict__ W2b,
                                              const float* __restrict__ b2,
                                              float* __restrict__ outp) {
    __shared__ __align__(16) u16 Qs[16 * 520];
    __shared__ __align__(16) u16 Vt[512 * 40];
    __shared__ float Sbuf[16 * 33];
    __shared__ __align__(16) u16 Pbuf[16 * 40];
    __shared__ float alpha_s[16];
    __shared__ float l_s[16];
    int b = blockIdx.x, qt = blockIdx.y;
    int tid = threadIdx.x, w = tid >> 6, l = tid & 63, quad = l >> 4, lane = l & 15;

    {   // prologue: Qs[16][512] = x_tile @ Wm^T + bm  (x cvt once per kk; Wm pre-cast)
        const float* xq = x + ((size_t)b * NL + qt * 16 + lane) * ND;
        f32x4 aq0 = {}, aq1 = {}, aq2 = {}, aq3 = {};
#pragma unroll 4
        for (int kk = 0; kk < 16; kk++) {
            bf16x8 a = cvt8(&xq[kk * 32 + quad * 8]);
            int koff = kk * 32 + quad * 8;
            aq0 = MF(a, *(const bf16x8*)&Wmb[(size_t)((w * 4 + 0) * 16 + lane) * ND + koff], aq0);
            aq1 = MF(a, *(const bf16x8*)&Wmb[(size_t)((w * 4 + 1) * 16 + lane) * ND + koff], aq1);
            aq2 = MF(a, *(const bf16x8*)&Wmb[(size_t)((w * 4 + 2) * 16 + lane) * ND + koff], aq2);
            aq3 = MF(a, *(const bf16x8*)&Wmb[(size_t)((w * 4 + 3) * 16 + lane) * ND + koff], aq3);
        }
        f32x4 aqs[4] = {aq0, aq1, aq2, aq3};
#pragma unroll
        for (int nt2 = 0; nt2 < 4; nt2++) {
            int n = (w * 4 + nt2) * 16 + lane;
            float bmv = bm[n];
#pragma unroll
            for (int r = 0; r < 4; r++)
                Qs[(quad * 4 + r) * 520 + n] = f2b(aqs[nt2][r] + bmv);
        }
    }
    float m_run = -30000.f, l_run = 0.f;
    f32x4 acc[4] = {};
    __syncthreads();

    int st_max = ((qt << 4) + 15) >> 5;
    for (int st = 0; st <= st_max; st++) {
        if (w < 2) {  // QK^T: S[16][32], waves 0..1
            int ni = w;
            f32x4 s = {};
            const u16* krow = kv + ((size_t)b * NL + st * 32 + ni * 16 + lane) * NH;
#pragma unroll 4
            for (int kk = 0; kk < 16; kk++)
                s = MF(*(bf16x8*)&Qs[lane * 520 + kk * 32 + quad * 8],
                       *(const bf16x8*)&krow[kk * 32 + quad * 8], s);
            int scol = st * 32 + ni * 16 + lane;
#pragma unroll
            for (int r = 0; r < 4; r++) {
                int trow = (qt << 4) + quad * 4 + r;
                int dt = trow - scol;
                float v = (dt < 0) ? -30000.f : s[r] * __expf(-0.6f * (float)dt);
                Sbuf[(quad * 4 + r) * 33 + ni * 16 + lane] = v;
            }
        } else if (w >= 4) {  // stage V^T[512][32]
            int t2 = tid & 255;
            int srow = t2 >> 3, dseg = t2 & 7;
            const u16* vsrc = kv + ((size_t)b * NL + st * 32 + srow) * NH + dseg * 64;
#pragma unroll
            for (int i = 0; i < 8; i++) {
                union { uint4 v; u16 h[8]; } u;
                u.v = *(const uint4*)&vsrc[i * 8];
                int d0 = dseg * 64 + i * 8;
#pragma unroll
                for (int j2 = 0; j2 < 8; j2++) Vt[(d0 + j2) * 40 + srow] = u.h[j2];
            }
        }
        __syncthreads();
        if (tid < 64) {  // wave-parallel online softmax: 4 lanes/row, 8 cols each
            int m = tid >> 2, c0 = (tid & 3) * 8;
            float vmax = -30000.f;
#pragma unroll
            for (int i = 0; i < 8; i++) vmax = fmaxf(vmax, Sbuf[m * 33 + c0 + i]);
            vmax = fmaxf(vmax, __shfl_xor(vmax, 1));
            vmax = fmaxf(vmax, __shfl_xor(vmax, 2));
            float mnew = fmaxf(m_run, vmax);
            float al = __expf(m_run - mnew);
            float lsum = 0.f;
#pragma unroll
            for (int i = 0; i < 8; i++) {
                float p = __expf(Sbuf[m * 33 + c0 + i] - mnew);
                lsum += p;
                Pbuf[m * 40 + c0 + i] = f2b(p);
            }
            lsum += __shfl_xor(lsum, 1);
            lsum += __shfl_xor(lsum, 2);
            l_run = l_run * al + lsum;
            m_run = mnew;
            if ((tid & 3) == 0) { alpha_s[m] = al; l_s[m] = l_run; }
        }
        __syncthreads();
        {   // PV
            float a0 = alpha_s[quad * 4 + 0];
            float a1 = alpha_s[quad * 4 + 1];
            float a2 = alpha_s[quad * 4 + 2];
            float a3 = alpha_s[quad * 4 + 3];
            bf16x8 afrag = *(bf16x8*)&Pbuf[lane * 40 + quad * 8];
#pragma unroll
            for (int di = 0; di < 4; di++) {
                int dtile = w * 4 + di;
                f32x4 c = acc[di];
                c[0] *= a0; c[1] *= a1; c[2] *= a2; c[3] *= a3;
                acc[di] = MF(afrag, *(bf16x8*)&Vt[(dtile * 16 + lane) * 40 + quad * 8], c);
            }
        }
        __syncthreads();
    }

    u16* Wt = Vt;   // weighted -> LDS
    {
        float li0 = 1.f / l_s[quad * 4 + 0];
        float li1 = 1.f / l_s[quad * 4 + 1];
        float li2 = 1.f / l_s[quad * 4 + 2];
        float li3 = 1.f / l_s[quad * 4 + 3];
#pragma unroll
        for (int di = 0; di < 4; di++) {
            int col = (w * 4 + di) * 16 + lane;
            Wt[(quad * 4 + 0) * 520 + col] = f2b(acc[di][0] * li0);
            Wt[(quad * 4 + 1) * 520 + col] = f2b(acc[di][1] * li1);
            Wt[(quad * 4 + 2) * 520 + col] = f2b(acc[di][2] * li2);
            Wt[(quad * 4 + 3) * 520 + col] = f2b(acc[di][3] * li3);
        }
    }
    __syncthreads();
    u16* H1 = Qs;
    {   // H1[16][256] = relu(Wt @ W1^T + b1)  (W1 pre-cast)
#pragma unroll
        for (int nt2 = 0; nt2 < 2; nt2++) {
            int n = (w * 2 + nt2) * 16 + lane;
            const u16* w1p = W1b + (size_t)n * ND;
            f32x4 a1 = {};
#pragma unroll 4
            for (int kk = 0; kk < 16; kk++)
                a1 = MF(*(bf16x8*)&Wt[lane * 520 + kk * 32 + quad * 8],
                        *(const bf16x8*)&w1p[kk * 32 + quad * 8], a1);
            float b1v = b1[n];
#pragma unroll
            for (int r = 0; r < 4; r++)
                H1[(quad * 4 + r) * 264 + n] = f2b(fmaxf(a1[r] + b1v, 0.f));
        }
    }
    __syncthreads();
    if (w < 7) {  // out[16][100] = H1 @ W2^T + b2  (W2 pre-cast)
        int n = w * 16 + lane;
        int nc = n < NOUT ? n : NOUT - 1;
        const u16* w2p = W2b + (size_t)nc * NFF;
        f32x4 a2 = {};
#pragma unroll
        for (int kk = 0; kk < 8; kk++)
            a2 = MF(*(bf16x8*)&H1[lane * 264 + kk * 32 + quad * 8],
                    *(const bf16x8*)&w2p[kk * 32 + quad * 8], a2);
        if (n < NOUT) {
            float b2v = b2[n];
#pragma unroll
            for (int r = 0; r < 4; r++)
                outp[((size_t)b * NL + (qt << 4) + quad * 4 + r) * NOUT + n] = a2[r] + b2v;
        }
    }
}

extern "C" void kernel_launch(void* const* d_in, const int* in_sizes, int n_in,
                              void* d_out, int out_size, void* d_ws, size_t ws_size,
                              hipStream_t stream) {
    const float* x        = (const float*)d_in[0];
    const int*   concepts = (const int*)d_in[1];
    const float* emb      = (const float*)d_in[2];
    const float* Wih      = (const float*)d_in[3];
    const float* Whh      = (const float*)d_in[4];
    const float* bih      = (const float*)d_in[5];
    const float* bhh      = (const float*)d_in[6];
    const float* Wm       = (const float*)d_in[7];
    const float* bm       = (const float*)d_in[8];
    const float* W1       = (const float*)d_in[9];
    const float* b1       = (const float*)d_in[10];
    const float* W2       = (const float*)d_in[11];
    const float* b2       = (const float*)d_in[12];
    float* outp = (float*)d_out;

    char* ws = (char*)d_ws;
    size_t off = 0;
    u16* lstm_out = (u16*)(ws + off); off += (size_t)NB * NL * NH * 2;   // 32 MB
    float* cbias  = (float*)(ws + off); off += (size_t)NB * G4 * 4;      // 256 KB
    u32x4* hx     = (u32x4*)(ws + off); off += (size_t)8 * 768 * 16;     // 96 KB tagged h units
    u16* Wmb      = (u16*)(ws + off); off += (size_t)ND * ND * 2;        // 512 KB
    u16* W1b      = (u16*)(ws + off); off += (size_t)NFF * ND * 2;       // 256 KB
    u16* W2b      = (u16*)(ws + off); off += (size_t)NOUT * NFF * 2;     // 50 KB

    (void)hipMemsetAsync(hx, 0, (size_t)8 * 768 * 16, stream);  // tags=0 != any expected tag
    k_wcast<<<(ND * ND / 4 + 255) / 256, 256, 0, stream>>>(Wm, Wmb, ND * ND / 4);
    k_wcast<<<(NFF * ND / 4 + 255) / 256, 256, 0, stream>>>(W1, W1b, NFF * ND / 4);
    k_wcast<<<(NOUT * NFF / 4 + 255) / 256, 256, 0, stream>>>(W2, W2b, NOUT * NFF / 4);
    k_cbias<<<dim3(NB, G4 / 256), 256, 0, stream>>>(emb, concepts, Wih, bih, bhh, cbias);
    k_lstm<<<256, 256, 0, stream>>>(x, Wih, Whh, cbias, lstm_out, hx);
    k_attn<<<dim3(NB, NL / 16), 512, 0, stream>>>(x, Wmb, bm, lstm_out, W1b, b1, W2b, b2, outp);
}

// Round 7
// 2206.287 us; speedup vs baseline: 2.1333x; 1.0962x over previous
//
#include <hip/hip_runtime.h>
#include <hip/hip_bf16.h>
#include <stdint.h>

typedef unsigned short u16;
typedef unsigned int u32;
typedef unsigned long long u64;
typedef float f32x4 __attribute__((ext_vector_type(4)));
typedef short bf16x8 __attribute__((ext_vector_type(8)));
typedef unsigned u32x4 __attribute__((ext_vector_type(4)));   // native vector for asm 'v'

#define NB 32
#define NL 1024
#define ND 512
#define NH 512
#define G4 2048
#define NOUT 100
#define NFF 256
#define HSTR 528   // LDS row stride (halfwords): 264 dwords == 8 mod 32 -> uniform 2-way (free) a-frag reads

__device__ inline u16 f2b(float f) {
    union { float f; unsigned i; } c; c.f = f;
    unsigned i = c.i;
    return (u16)((i + 0x7FFFu + ((i >> 16) & 1u)) >> 16);
}
__device__ inline bf16x8 cvt8(const float* __restrict__ p) {
    float4 a = *(const float4*)p;
    float4 b = *(const float4*)(p + 4);
    bf16x8 r;
    u16* h = (u16*)&r;
    h[0] = f2b(a.x); h[1] = f2b(a.y); h[2] = f2b(a.z); h[3] = f2b(a.w);
    h[4] = f2b(b.x); h[5] = f2b(b.y); h[6] = f2b(b.z); h[7] = f2b(b.w);
    return r;
}
__device__ inline f32x4 MF(bf16x8 a, bf16x8 b, f32x4 c) {
    return __builtin_amdgcn_mfma_f32_16x16x32_bf16(a, b, c, 0, 0, 0);
}
__device__ inline float tanh_f(float x) {
    float xx = fminf(fmaxf(x, -15.f), 15.f);
    float e = __expf(2.f * xx);
    return (e - 1.f) / (e + 1.f);
}
__device__ inline float sigm_f(float x) { return 1.f / (1.f + __expf(-x)); }

// 16-B SYSTEM-coherent load/store (sc0 sc1: scope >= agent, to the coherence point).
// One dwordx4 = one LLC request -> tag+payload move atomically within the aligned 16 B.
__device__ inline u32x4 ld_sc16(const u32x4* p) {
    u32x4 r;
    asm volatile("global_load_dwordx4 %0, %1, off sc0 sc1\n\t"
                 "s_waitcnt vmcnt(0)"
                 : "=&v"(r) : "v"(p) : "memory");
    return r;
}
__device__ inline void ld2_issue(const u32x4* p1, const u32x4* p2, u32x4& r1, u32x4& r2) {
    asm volatile("global_load_dwordx4 %0, %2, off sc0 sc1\n\t"
                 "global_load_dwordx4 %1, %3, off sc0 sc1"
                 : "=&v"(r1), "=&v"(r2) : "v"(p1), "v"(p2) : "memory");
}
__device__ inline void wait_vm2(u32x4& r1, u32x4& r2) {
    asm volatile("s_waitcnt vmcnt(0)" : "+v"(r1), "+v"(r2) :: "memory");
}
__device__ inline void st_sc16(u32x4* p, u32x4 v) {
    asm volatile("global_store_dwordx4 %0, %1, off sc0 sc1"
                 :: "v"(p), "v"(v) : "memory");
}

// f32 -> bf16 pre-cast (weights for k_attn): one quad per thread.
__global__ __launch_bounds__(256) void k_wcast(const float* __restrict__ s,
                                               u16* __restrict__ d, int n4) {
    int i = blockIdx.x * 256 + threadIdx.x;
    if (i >= n4) return;
    float4 v = *(const float4*)&s[(size_t)i * 4];
    u64 pk = (u64)f2b(v.x) | ((u64)f2b(v.y) << 16) |
             ((u64)f2b(v.z) << 32) | ((u64)f2b(v.w) << 48);
    *(u64*)&d[(size_t)i * 4] = pk;
}

// cbias[b][r] = emb[concepts[b]] . Wih[r, 512:1024] + bih[r] + bhh[r]   (all fp32)
__global__ __launch_bounds__(256) void k_cbias(const float* __restrict__ emb,
                                               const int* __restrict__ concepts,
                                               const float* __restrict__ Wih,
                                               const float* __restrict__ bih,
                                               const float* __restrict__ bhh,
                                               float* __restrict__ cbias) {
    __shared__ float e[ND];
    int b = blockIdx.x;
    int r = blockIdx.y * 256 + threadIdx.x;
    int c = concepts[b];
    for (int i = threadIdx.x; i < ND; i += 256) e[i] = emb[c * ND + i];
    __syncthreads();
    const float* wrow = Wih + (size_t)r * 1024 + 512;
    float acc = 0.f;
#pragma unroll 4
    for (int k4 = 0; k4 < 128; k4++) {
        float4 wv = *(const float4*)&wrow[k4 * 4];
        acc += e[k4 * 4 + 0] * wv.x + e[k4 * 4 + 1] * wv.y +
               e[k4 * 4 + 2] * wv.z + e[k4 * 4 + 3] * wv.w;
    }
    cbias[b * G4 + r] = acc + bih[r] + bhh[r];
}

// Persistent LSTM, batch-split: 8 groups x 32 blocks; group g owns batch rows [4g,4g+4),
// block k owns h lanes [16k,16k+16).
// v8: wave-local cell (NO gbuf, NO barrier B, NO cb_lds) via gate-interleaved B-operand:
//  - B col n = (gate = n&3, h-col = jj + w*4 + (n>>2)) -> each wave's C holds all 4 gates
//    for 4 h-cols x 4 batch rows. Cell gathered in-wave: 3 shfl_xor (masks 1,2,3) move
//    gate quartets between the 4 lanes of each column group. ONE barrier per step (C).
//  - Publish moves ~300 cy earlier (right after cell, no cross-wave epilogue), shortening
//    the producer->consumer chain that gates every block's next step.
//  - Exchange: 512 units/group {4 bf16 | pad | tag=t+1}, exactly 2 per thread (uniform).
//    Spin loads issued before x-MFMA, waited after (v7-validated overlap). hsb staging
//    needs no extra sync: a wave can only reach its t+1 staging after ALL waves published
//    h[t], which happens after their t-step hsb reads (exchange-ordering).
//  - Weights in regs, HSTR=528, depth-2 x prefetch, guard-bounded spins (all validated).
__global__ __launch_bounds__(256, 1) void k_lstm(const float* __restrict__ x,
                                                 const float* __restrict__ Wih,
                                                 const float* __restrict__ Whh,
                                                 const float* __restrict__ cbias,
                                                 u16* __restrict__ out,
                                                 u32x4* __restrict__ hx) {
    __shared__ __align__(16) u16 hsb[4 * HSTR];         // h[t-1] tile, bf16
    __shared__ __align__(16) u16 xb[2][4 * HSTR];       // x double buffer, bf16
    int g = blockIdx.x & 7, k = blockIdx.x >> 3;
    int tid = threadIdx.x;
    int w = tid >> 6, l = tid & 63, quad = l >> 4, lane = l & 15;
    int jj = k * 16;
    int b0 = g * 4;
    int rr = w, f0 = l * 8;
    int gidx = l & 3;          // gate index of this lane's C column
    int cidx = lane >> 2;      // h-col offset (0..3) within the wave's 4 columns

    // ---- init: weights -> registers (gate-interleaved B cols), cbias regs, x[0] -> LDS
    bf16x8 bwx[16], bwh[16];
    float cbv0, cbv1, cbv2, cbv3;
    {
        int n = lane;                       // B col
        int wrow = (n & 3) * 512 + jj + w * 4 + (n >> 2);   // weight row for col n
        int q4 = l >> 4;
        const float* wsrc = Wih + (size_t)wrow * 1024 + q4 * 8;  // x-part
        const float* hsrc = Whh + (size_t)wrow * 512 + q4 * 8;
#pragma unroll
        for (int kk = 0; kk < 16; kk++) {
            bwx[kk] = cvt8(wsrc + kk * 32);
            bwh[kk] = cvt8(hsrc + kk * 32);
        }
        // cell constants for (row=gidx, col=jj+w*4+cidx), one per gate
        size_t cb = (size_t)(b0 + gidx) * G4 + jj + w * 4 + cidx;
        cbv0 = cbias[cb + 0 * 512];
        cbv1 = cbias[cb + 1 * 512];
        cbv2 = cbias[cb + 2 * 512];
        cbv3 = cbias[cb + 3 * 512];
        *(bf16x8*)&xb[0][rr * HSTR + f0] = cvt8(&x[((size_t)(b0 + rr) * NL) * ND + f0]);
    }

    // ---- consumer precompute: 512 units (32 blocks x 4 rows x 4 waves), exactly 2/thread
    // unit u = p*16 + r*4 + wv: payload = h[row r][p*16 + wv*4 .. +3]
    u32x4* hxg = hx + (size_t)g * 1024;              // per-group: 2 parity x 512 units
    int p1 = tid >> 4, r1 = (tid >> 2) & 3, w1 = tid & 3;
    int lo1 = r1 * HSTR + p1 * 16 + w1 * 4;          // hsb halfword offset (unit 1)
    int lo2 = lo1 + 256;                             // unit 2: p += 16
    const u32x4* a1base = hxg + tid;
    const u32x4* a2base = hxg + 256 + tid;
    u32x4* myst = hxg + k * 16 + w;                  // + r*4 chosen by builder lane

    // preload x[1] into prefetch regs (committed at top of iter 0)
    float4 pa, pb;
    {
        const float* px = &x[((size_t)(b0 + rr) * NL + 1) * ND + f0];
        pa = *(const float4*)px; pb = *(const float4*)(px + 4);
    }
    __syncthreads();

    float c_reg = 0.f;   // cell state for (row gidx, col jj+w*4+cidx); dup across quads

    for (int t = 0; t < NL; t++) {
        // ---- commit x[t+1] (loads issued one full iteration ago; after barrier C(t-1))
        if (t + 1 < NL) {
            bf16x8 xv; u16* hh = (u16*)&xv;
            hh[0] = f2b(pa.x); hh[1] = f2b(pa.y); hh[2] = f2b(pa.z); hh[3] = f2b(pa.w);
            hh[4] = f2b(pb.x); hh[5] = f2b(pb.y); hh[6] = f2b(pb.z); hh[7] = f2b(pb.w);
            *(bf16x8*)&xb[(t + 1) & 1][rr * HSTR + f0] = xv;
        }
        // ---- issue spin loads EARLY (latency hides under x-MFMA)
        u32x4 A1 = {}, A2 = {};
        const u32x4* A1p = a1base;
        const u32x4* A2p = a2base;
        if (t > 0) {
            int poff = ((t - 1) & 1) * 512;
            A1p = a1base + poff;
            A2p = a2base + poff;
            ld2_issue(A1p, A2p, A1, A2);
        }
        // ---- x-part MFMA, 4 independent accumulator chains (LDS/lgkm only)
        f32x4 ac0 = {}, ac1 = {}, ac2 = {}, ac3 = {};
#pragma unroll
        for (int kk = 0; kk < 16; kk += 4) {
            const u16* xbp = &xb[t & 1][(lane & 3) * HSTR + quad * 8];
            ac0 = MF(*(bf16x8*)&xbp[(kk + 0) * 32], bwx[kk + 0], ac0);
            ac1 = MF(*(bf16x8*)&xbp[(kk + 1) * 32], bwx[kk + 1], ac1);
            ac2 = MF(*(bf16x8*)&xbp[(kk + 2) * 32], bwx[kk + 2], ac2);
            ac3 = MF(*(bf16x8*)&xbp[(kk + 3) * 32], bwx[kk + 3], ac3);
        }
        if (t > 0) {
            // ---- wait + tagged spin (first check usually fresh: load overlapped MFMA)
            wait_vm2(A1, A2);
            __builtin_amdgcn_sched_barrier(0);
            int guard = 0;
            while (A1.w != (u32)t) {
                if (++guard > (1 << 22)) break;   // hang-proof: fail, never hang
                __builtin_amdgcn_s_sleep(1);
                A1 = ld_sc16(A1p);
            }
            guard = 0;
            while (A2.w != (u32)t) {
                if (++guard > (1 << 22)) break;
                __builtin_amdgcn_s_sleep(1);
                A2 = ld_sc16(A2p);
            }
            *(u32*)&hsb[lo1] = A1.x; *(u32*)&hsb[lo1 + 2] = A1.y;
            *(u32*)&hsb[lo2] = A2.x; *(u32*)&hsb[lo2 + 2] = A2.y;
        }
        // ---- issue x[t+2] prefetch (post-spin: spin's vmcnt never waits on these)
        if (t + 2 < NL) {
            const float* px = &x[((size_t)(b0 + rr) * NL + (t + 2)) * ND + f0];
            pa = *(const float4*)px; pb = *(const float4*)(px + 4);
        }
        __syncthreads();   // (C) hsb + xb ready for all waves
        if (t > 0) {
            // ---- h-part MFMA into the same 4 chains
#pragma unroll
            for (int kk = 0; kk < 16; kk += 4) {
                const u16* hbp = &hsb[(lane & 3) * HSTR + quad * 8];
                ac0 = MF(*(bf16x8*)&hbp[(kk + 0) * 32], bwh[kk + 0], ac0);
                ac1 = MF(*(bf16x8*)&hbp[(kk + 1) * 32], bwh[kk + 1], ac1);
                ac2 = MF(*(bf16x8*)&hbp[(kk + 2) * 32], bwh[kk + 2], ac2);
                ac3 = MF(*(bf16x8*)&hbp[(kk + 3) * 32], bwh[kk + 3], ac3);
            }
        }
        f32x4 acc = (ac0 + ac1) + (ac2 + ac3);
        {   // ---- wave-local cell: gather the 4 gates of (row gidx, col cidx) via shfl_xor.
            // Every lane sends acc[own_g ^ m]; receives partner's acc[own_g] = gate (g^m).
            float a0 = acc[0], a1 = acc[1], a2 = acc[2], a3 = acc[3];
            // dynamic extract acc[i] (i = gidx ^ m), ~3 cndmask each — no scratch
            auto ext = [&](int i) {
                float t01 = (i & 1) ? a1 : a0;
                float t23 = (i & 1) ? a3 : a2;
                return (i & 2) ? t23 : t01;
            };
            float own = ext(gidx);
            float r1v = __shfl_xor(ext(gidx ^ 1), 1);
            float r2v = __shfl_xor(ext(gidx ^ 2), 2);
            float r3v = __shfl_xor(ext(gidx ^ 3), 3);
            // gate j value = X[gidx ^ j], X = {own, r1v, r2v, r3v}
            auto pick = [&](int i) {
                float t01 = (i & 1) ? r1v : own;
                float t23 = (i & 1) ? r3v : r2v;
                return (i & 2) ? t23 : t01;
            };
            float gi = pick(gidx) + cbv0;        // gate 0 (i):  gidx ^ 0
            float gf = pick(gidx ^ 1) + cbv1;    // gate 1 (f)
            float gg = pick(gidx ^ 2) + cbv2;    // gate 2 (g)
            float go = pick(gidx ^ 3) + cbv3;    // gate 3 (o)
            float iv = sigm_f(gi), fv = sigm_f(gf), ov = sigm_f(go);
            float gv = tanh_f(gg);
            c_reg = fv * c_reg + iv * gv;
            unsigned h32 = (unsigned)f2b(ov * tanh_f(c_reg));
            // publish: builder lane r (<4) gathers its row's 4 cols from lanes r,4+r,8+r,12+r
            unsigned s1 = __shfl(h32, (l & 3) + 4);
            unsigned s2 = __shfl(h32, (l & 3) + 8);
            unsigned s3 = __shfl(h32, (l & 3) + 12);
            if (l < 4) {
                u32x4 U;
                U.x = h32 | (s1 << 16);
                U.y = s2 | (s3 << 16);
                U.z = 0u;
                U.w = (u32)(t + 1);
                st_sc16(myst + (t & 1) * 512 + l * 4, U);
                // lstm_out write off the sync path (row l, cols jj+w*4..+3)
                *(u64*)&out[((size_t)(b0 + l) * NL + t) * NH + jj + w * 4] =
                    (u64)U.x | ((u64)U.y << 32);
            }
        }
    }
}

// Fused: Q = x@Wm^T+bm (prologue), flash attention with decayed-causal scores,
// FF head relu(W@W1^T+b1)@W2^T+b2 (epilogue). 16-row q tiles, 512 threads.
// (v7-validated: bf16 pre-cast weights, single-cvt prologue, wave-parallel softmax.)
__global__ __launch_bounds__(512) void k_attn(const float* __restrict__ x,
                                              const u16* __restrict__ Wmb,
                                              const float* __restrict__ bm,
                                              const u16* __restrict__ kv,
                                              const u16* __restrict__ W1b,
                                              const float* __restrict__ b1,
                                              const u16* __restrict__ W2b,
                                              const float* __restrict__ b2,
                                              float* __restrict__ outp) {
    __shared__ __align__(16) u16 Qs[16 * 520];
    __shared__ __align__(16) u16 Vt[512 * 40];
    __shared__ float Sbuf[16 * 33];
    __shared__ __align__(16) u16 Pbuf[16 * 40];
    __shared__ float alpha_s[16];
    __shared__ float l_s[16];
    int b = blockIdx.x, qt = blockIdx.y;
    int tid = threadIdx.x, w = tid >> 6, l = tid & 63, quad = l >> 4, lane = l & 15;

    {   // prologue: Qs[16][512] = x_tile @ Wm^T + bm
        const float* xq = x + ((size_t)b * NL + qt * 16 + lane) * ND;
        f32x4 aq0 = {}, aq1 = {}, aq2 = {}, aq3 = {};
#pragma unroll 4
        for (int kk = 0; kk < 16; kk++) {
            bf16x8 a = cvt8(&xq[kk * 32 + quad * 8]);
            int koff = kk * 32 + quad * 8;
            aq0 = MF(a, *(const bf16x8*)&Wmb[(size_t)((w * 4 + 0) * 16 + lane) * ND + koff], aq0);
            aq1 = MF(a, *(const bf16x8*)&Wmb[(size_t)((w * 4 + 1) * 16 + lane) * ND + koff], aq1);
            aq2 = MF(a, *(const bf16x8*)&Wmb[(size_t)((w * 4 + 2) * 16 + lane) * ND + koff], aq2);
            aq3 = MF(a, *(const bf16x8*)&Wmb[(size_t)((w * 4 + 3) * 16 + lane) * ND + koff], aq3);
        }
        f32x4 aqs[4] = {aq0, aq1, aq2, aq3};
#pragma unroll
        for (int nt2 = 0; nt2 < 4; nt2++) {
            int n = (w * 4 + nt2) * 16 + lane;
            float bmv = bm[n];
#pragma unroll
            for (int r = 0; r < 4; r++)
                Qs[(quad * 4 + r) * 520 + n] = f2b(aqs[nt2][r] + bmv);
        }
    }
    float m_run = -30000.f, l_run = 0.f;
    f32x4 acc[4] = {};
    __syncthreads();

    int st_max = ((qt << 4) + 15) >> 5;
    for (int st = 0; st <= st_max; st++) {
        if (w < 2) {  // QK^T: S[16][32], waves 0..1
            int ni = w;
            f32x4 s = {};
            const u16* krow = kv + ((size_t)b * NL + st * 32 + ni * 16 + lane) * NH;
#pragma unroll 4
            for (int kk = 0; kk < 16; kk++)
                s = MF(*(bf16x8*)&Qs[lane * 520 + kk * 32 + quad * 8],
                       *(const bf16x8*)&krow[kk * 32 + quad * 8], s);
            int scol = st * 32 + ni * 16 + lane;
#pragma unroll
            for (int r = 0; r < 4; r++) {
                int trow = (qt << 4) + quad * 4 + r;
                int dt = trow - scol;
                float v = (dt < 0) ? -30000.f : s[r] * __expf(-0.6f * (float)dt);
                Sbuf[(quad * 4 + r) * 33 + ni * 16 + lane] = v;
            }
        } else if (w >= 4) {  // stage V^T[512][32]
            int t2 = tid & 255;
            int srow = t2 >> 3, dseg = t2 & 7;
            const u16* vsrc = kv + ((size_t)b * NL + st * 32 + srow) * NH + dseg * 64;
#pragma unroll
            for (int i = 0; i < 8; i++) {
                union { uint4 v; u16 h[8]; } u;
                u.v = *(const uint4*)&vsrc[i * 8];
                int d0 = dseg * 64 + i * 8;
#pragma unroll
                for (int j2 = 0; j2 < 8; j2++) Vt[(d0 + j2) * 40 + srow] = u.h[j2];
            }
        }
        __syncthreads();
        if (tid < 64) {  // wave-parallel online softmax: 4 lanes/row, 8 cols each
            int m = tid >> 2, c0 = (tid & 3) * 8;
            float vmax = -30000.f;
#pragma unroll
            for (int i = 0; i < 8; i++) vmax = fmaxf(vmax, Sbuf[m * 33 + c0 + i]);
            vmax = fmaxf(vmax, __shfl_xor(vmax, 1));
            vmax = fmaxf(vmax, __shfl_xor(vmax, 2));
            float mnew = fmaxf(m_run, vmax);
            float al = __expf(m_run - mnew);
            float lsum = 0.f;
#pragma unroll
            for (int i = 0; i < 8; i++) {
                float p = __expf(Sbuf[m * 33 + c0 + i] - mnew);
                lsum += p;
                Pbuf[m * 40 + c0 + i] = f2b(p);
            }
            lsum += __shfl_xor(lsum, 1);
            lsum += __shfl_xor(lsum, 2);
            l_run = l_run * al + lsum;
            m_run = mnew;
            if ((tid & 3) == 0) { alpha_s[m] = al; l_s[m] = l_run; }
        }
        __syncthreads();
        {   // PV
            float a0 = alpha_s[quad * 4 + 0];
            float a1 = alpha_s[quad * 4 + 1];
            float a2 = alpha_s[quad * 4 + 2];
            float a3 = alpha_s[quad * 4 + 3];
            bf16x8 afrag = *(bf16x8*)&Pbuf[lane * 40 + quad * 8];
#pragma unroll
            for (int di = 0; di < 4; di++) {
                int dtile = w * 4 + di;
                f32x4 c = acc[di];
                c[0] *= a0; c[1] *= a1; c[2] *= a2; c[3] *= a3;
                acc[di] = MF(afrag, *(bf16x8*)&Vt[(dtile * 16 + lane) * 40 + quad * 8], c);
            }
        }
        __syncthreads();
    }

    u16* Wt = Vt;   // weighted -> LDS
    {
        float li0 = 1.f / l_s[quad * 4 + 0];
        float li1 = 1.f / l_s[quad * 4 + 1];
        float li2 = 1.f / l_s[quad * 4 + 2];
        float li3 = 1.f / l_s[quad * 4 + 3];
#pragma unroll
        for (int di = 0; di < 4; di++) {
            int col = (w * 4 + di) * 16 + lane;
            Wt[(quad * 4 + 0) * 520 + col] = f2b(acc[di][0] * li0);
            Wt[(quad * 4 + 1) * 520 + col] = f2b(acc[di][1] * li1);
            Wt[(quad * 4 + 2) * 520 + col] = f2b(acc[di][2] * li2);
            Wt[(quad * 4 + 3) * 520 + col] = f2b(acc[di][3] * li3);
        }
    }
    __syncthreads();
    u16* H1 = Qs;
    {   // H1[16][256] = relu(Wt @ W1^T + b1)
#pragma unroll
        for (int nt2 = 0; nt2 < 2; nt2++) {
            int n = (w * 2 + nt2) * 16 + lane;
            const u16* w1p = W1b + (size_t)n * ND;
            f32x4 a1 = {};
#pragma unroll 4
            for (int kk = 0; kk < 16; kk++)
                a1 = MF(*(bf16x8*)&Wt[lane * 520 + kk * 32 + quad * 8],
                        *(const bf16x8*)&w1p[kk * 32 + quad * 8], a1);
            float b1v = b1[n];
#pragma unroll
            for (int r = 0; r < 4; r++)
                H1[(quad * 4 + r) * 264 + n] = f2b(fmaxf(a1[r] + b1v, 0.f));
        }
    }
    __syncthreads();
    if (w < 7) {  // out[16][100] = H1 @ W2^T + b2
        int n = w * 16 + lane;
        int nc = n < NOUT ? n : NOUT - 1;
        const u16* w2p = W2b + (size_t)nc * NFF;
        f32x4 a2 = {};
#pragma unroll
        for (int kk = 0; kk < 8; kk++)
            a2 = MF(*(bf16x8*)&H1[lane * 264 + kk * 32 + quad * 8],
                    *(const bf16x8*)&w2p[kk * 32 + quad * 8], a2);
        if (n < NOUT) {
            float b2v = b2[n];
#pragma unroll
            for (int r = 0; r < 4; r++)
                outp[((size_t)b * NL + (qt << 4) + quad * 4 + r) * NOUT + n] = a2[r] + b2v;
        }
    }
}

extern "C" void kernel_launch(void* const* d_in, const int* in_sizes, int n_in,
                              void* d_out, int out_size, void* d_ws, size_t ws_size,
                              hipStream_t stream) {
    const float* x        = (const float*)d_in[0];
    const int*   concepts = (const int*)d_in[1];
    const float* emb      = (const float*)d_in[2];
    const float* Wih      = (const float*)d_in[3];
    const float* Whh      = (const float*)d_in[4];
    const float* bih      = (const float*)d_in[5];
    const float* bhh      = (const float*)d_in[6];
    const float* Wm       = (const float*)d_in[7];
    const float* bm       = (const float*)d_in[8];
    const float* W1       = (const float*)d_in[9];
    const float* b1       = (const float*)d_in[10];
    const float* W2       = (const float*)d_in[11];
    const float* b2       = (const float*)d_in[12];
    float* outp = (float*)d_out;

    char* ws = (char*)d_ws;
    size_t off = 0;
    u16* lstm_out = (u16*)(ws + off); off += (size_t)NB * NL * NH * 2;   // 32 MB
    float* cbias  = (float*)(ws + off); off += (size_t)NB * G4 * 4;      // 256 KB
    u32x4* hx     = (u32x4*)(ws + off); off += (size_t)8 * 1024 * 16;    // 128 KB tagged h units
    u16* Wmb      = (u16*)(ws + off); off += (size_t)ND * ND * 2;        // 512 KB
    u16* W1b      = (u16*)(ws + off); off += (size_t)NFF * ND * 2;       // 256 KB
    u16* W2b      = (u16*)(ws + off); off += (size_t)NOUT * NFF * 2;     // 50 KB

    (void)hipMemsetAsync(hx, 0, (size_t)8 * 1024 * 16, stream);  // tags=0 != any expected tag
    k_wcast<<<(ND * ND / 4 + 255) / 256, 256, 0, stream>>>(Wm, Wmb, ND * ND / 4);
    k_wcast<<<(NFF * ND / 4 + 255) / 256, 256, 0, stream>>>(W1, W1b, NFF * ND / 4);
    k_wcast<<<(NOUT * NFF / 4 + 255) / 256, 256, 0, stream>>>(W2, W2b, NOUT * NFF / 4);
    k_cbias<<<dim3(NB, G4 / 256), 256, 0, stream>>>(emb, concepts, Wih, bih, bhh, cbias);
    k_lstm<<<256, 256, 0, stream>>>(x, Wih, Whh, cbias, lstm_out, hx);
    k_attn<<<dim3(NB, NL / 16), 512, 0, stream>>>(x, Wmb, bm, lstm_out, W1b, b1, W2b, b2, outp);
}